// Round 2
// baseline (868.391 us; speedup 1.0000x reference)
//
#include <hip/hip_runtime.h>
#include <math.h>

// Problem constants
constexpr int CB  = 8;      // batch B
constexpr int CL  = 2048;   // sequence length L
constexpr int CC  = 256;    // channels NC
constexpr int CNH = 8;      // heads
constexpr int CHC = 32;     // head channels
constexpr int CGC = 32;     // group channels
constexpr int CHW = 1024;   // H*W (32*32)
constexpr int CNS = 1024;   // n_sample
constexpr int CBG = 64;     // B * n_groups

// Workspace layout (floats)
constexpr size_t WS_QPOOL = 0;            // 2048
constexpr size_t WS_MSUM  = 2048;         // 8
constexpr size_t WS_QCOND = 2176;         // 2048
constexpr size_t WS_QT    = 4224;         // 2,097,152  (8,256,32,32)
constexpr size_t WS_POS   = 2101376;      // 131,072    (64,32,32,2)
constexpr size_t WS_XS    = 2232448;      // 2,097,152  (8,256,1024)
constexpr size_t WS_K     = 4329600;      // 2,097,152
constexpr size_t WS_V     = 6426752;      // 2,097,152
constexpr size_t WS_TMP   = 8523904;      // 4,194,304  (8,2048,256)
constexpr size_t WS_WOT   = 12718208;     // 65,536

// ---------------- K1: masked mean pool (partial sums via atomics) -------------
__global__ void k_pool(const float* __restrict__ q, const float* __restrict__ mask,
                       float* __restrict__ qpool, float* __restrict__ msum) {
  int b  = blockIdx.x >> 5;   // 8
  int lc = blockIdx.x & 31;   // 32 chunks of 64 rows
  int l0 = lc * 64;
  int tid = threadIdx.x;
  __shared__ float mloc[64];
  if (tid < 64) mloc[tid] = mask[b * CL + l0 + tid];
  __syncthreads();
  if (tid == 0) {
    float s = 0.f;
    for (int j = 0; j < 64; j++) s += mloc[j];
    atomicAdd(&msum[b], s);
  }
  float acc = 0.f;
  const float* qb = q + (size_t)(b * CL + l0) * CC + tid;
  for (int j = 0; j < 64; j++) acc += qb[(size_t)j * CC] * mloc[j];
  atomicAdd(&qpool[b * CC + tid], acc);
}

// ---------------- K2: q_cond = pooled_mean @ Wq.T + bq ----------------------
__global__ void k_qcond(const float* __restrict__ qpool, const float* __restrict__ msum,
                        const float* __restrict__ Wq, const float* __restrict__ bq,
                        float* __restrict__ qcond) {
  int b = blockIdx.x, o = threadIdx.x;
  __shared__ float qm[CC];
  float inv = 1.f / (msum[b] + 1e-6f);
  qm[o] = qpool[b * CC + o] * inv;
  __syncthreads();
  float acc = bq[o];
  const float* wrow = Wq + (size_t)o * CC;
  for (int i = 0; i < CC; i++) acc += wrow[i] * qm[i];
  qcond[b * CC + o] = acc;
}

// ---------------- K2b: transpose Wo for coalesced reads in yproj ------------
__global__ void k_transpose(const float* __restrict__ Wo, float* __restrict__ WoT) {
  int o = blockIdx.x, i = threadIdx.x;
  WoT[(size_t)i * CC + o] = Wo[(size_t)o * CC + i];
}

// ---------------- K3: modulated 1x1 conv (16 out-ch per block) --------------
__global__ void k_mod(const float* __restrict__ x, const float* __restrict__ qcond,
                      const float* __restrict__ Wmod, float* __restrict__ qt) {
  int b  = blockIdx.x >> 4;   // 8
  int og = blockIdx.x & 15;   // 16 o-groups of 16
  int tid = threadIdx.x;
  __shared__ float wl[CC * 16];   // wl[i*16+oo]
  __shared__ float dl[16];
  float qi = qcond[b * CC + tid] + 1.f;
  #pragma unroll
  for (int oo = 0; oo < 16; oo++)
    wl[tid * 16 + oo] = Wmod[(size_t)(og * 16 + oo) * CC + tid] * qi;
  __syncthreads();
  if (tid < 16) {
    float s = 0.f;
    for (int i = 0; i < CC; i++) { float w = wl[i * 16 + tid]; s += w * w; }
    dl[tid] = rsqrtf(s + 1e-8f);
  }
  __syncthreads();
  const float* xb = x + (size_t)(b & 1) * CC * CHW + tid * 4;
  float4 acc[16];
  #pragma unroll
  for (int oo = 0; oo < 16; oo++) acc[oo] = make_float4(0.f, 0.f, 0.f, 0.f);
  for (int i = 0; i < CC; i++) {
    float4 xv = *(const float4*)(xb + (size_t)i * CHW);
    const float4* wv4 = (const float4*)(wl + i * 16);
    #pragma unroll
    for (int g4 = 0; g4 < 4; g4++) {
      float4 w4 = wv4[g4];
      acc[g4*4+0].x += w4.x*xv.x; acc[g4*4+0].y += w4.x*xv.y; acc[g4*4+0].z += w4.x*xv.z; acc[g4*4+0].w += w4.x*xv.w;
      acc[g4*4+1].x += w4.y*xv.x; acc[g4*4+1].y += w4.y*xv.y; acc[g4*4+1].z += w4.y*xv.z; acc[g4*4+1].w += w4.y*xv.w;
      acc[g4*4+2].x += w4.z*xv.x; acc[g4*4+2].y += w4.z*xv.y; acc[g4*4+2].z += w4.z*xv.z; acc[g4*4+2].w += w4.z*xv.w;
      acc[g4*4+3].x += w4.w*xv.x; acc[g4*4+3].y += w4.w*xv.y; acc[g4*4+3].z += w4.w*xv.z; acc[g4*4+3].w += w4.w*xv.w;
    }
  }
  #pragma unroll
  for (int oo = 0; oo < 16; oo++) {
    float d = dl[oo];
    float4 r = acc[oo];
    r.x *= d; r.y *= d; r.z *= d; r.w *= d;
    *(float4*)(qt + ((size_t)(b * CC + og * 16 + oo)) * CHW + tid * 4) = r;
  }
}

// ------- K4: dwconv3x3 + LN + GELU + offset proj + tanh + ref -> pos --------
__global__ void k_off(const float* __restrict__ qt, const float* __restrict__ dww,
                      const float* __restrict__ dwb, const float* __restrict__ lnw,
                      const float* __restrict__ lnb, const float* __restrict__ offw,
                      float* __restrict__ posw, float* __restrict__ out_pos,
                      float* __restrict__ out_ref) {
  int bg   = blockIdx.x >> 7;
  int pblk = blockIdx.x & 127;
  int tid  = threadIdx.x;
  int c = tid & 31, pp = tid >> 5;          // 32 channels x 8 positions
  int p0 = pblk * 8;
  int yy = p0 >> 5;                          // row (same for the 8 positions)
  int xx = (p0 & 31) + pp;                   // column
  int p  = p0 + pp;
  const float* src = qt + ((size_t)bg * CGC + c) * CHW;
  float acc = dwb[c];
  #pragma unroll
  for (int ky = 0; ky < 3; ky++) {
    int yr = yy + ky - 1;
    if (yr < 0 || yr > 31) continue;
    #pragma unroll
    for (int kx = 0; kx < 3; kx++) {
      int xc = xx + kx - 1;
      if (xc < 0 || xc > 31) continue;
      acc += dww[c * 9 + ky * 3 + kx] * src[yr * 32 + xc];
    }
  }
  // LayerNorm over the 32 channels (c lives in the low 5 lane bits)
  float s1 = acc, s2 = acc * acc;
  #pragma unroll
  for (int m = 1; m < 32; m <<= 1) { s1 += __shfl_xor(s1, m, 32); s2 += __shfl_xor(s2, m, 32); }
  float mu  = s1 * (1.f / 32.f);
  float var = s2 * (1.f / 32.f) - mu * mu;
  float tn  = (acc - mu) * rsqrtf(var + 1e-5f) * lnw[c] + lnb[c];
  float g   = 0.5f * tn * (1.f + erff(tn * 0.70710678118654752f));
  float sy = offw[c] * g, sx = offw[32 + c] * g;
  #pragma unroll
  for (int m = 1; m < 32; m <<= 1) { sy += __shfl_xor(sy, m, 32); sx += __shfl_xor(sx, m, 32); }
  if (c < 2) {
    float v   = (c == 0) ? sy : sx;
    float off = tanhf(v) * (2.f / 31.f);
    float coord = (c == 0) ? (float)yy : (float)xx;
    float ref = (0.5f + coord) * (2.f / 31.f) - 1.f;
    float pv  = off + ref;
    int oidx = bg * 2048 + p * 2 + c;
    posw[oidx]    = pv;
    out_pos[oidx] = pv;
    out_ref[oidx] = ref;
  }
}

// ---------------- K5: bilinear grid sample (zero padding) -------------------
__global__ void k_sample(const float* __restrict__ x, const float* __restrict__ posw,
                         float* __restrict__ xs) {
  int bg   = blockIdx.x >> 7;
  int pblk = blockIdx.x & 127;
  int tid  = threadIdx.x;
  int c = tid >> 3, pp = tid & 7;
  int p = pblk * 8 + pp;
  float py = posw[bg * 2048 + p * 2 + 0];
  float px = posw[bg * 2048 + p * 2 + 1];
  float gx = (px + 1.f) * 15.5f;
  float gy = (py + 1.f) * 15.5f;
  float x0f = floorf(gx), y0f = floorf(gy);
  float wx = gx - x0f, wy = gy - y0f;
  int ix0 = (int)x0f, iy0 = (int)y0f;
  const float* img = x + (size_t)((bg >> 3) & 1) * CC * CHW + ((size_t)((bg & 7) * CGC + c)) * CHW;
  float acc = 0.f;
  #pragma unroll
  for (int dy = 0; dy < 2; dy++) {
    int iy = iy0 + dy;
    if (iy < 0 || iy > 31) continue;
    float wyv = dy ? wy : 1.f - wy;
    #pragma unroll
    for (int dx = 0; dx < 2; dx++) {
      int ix = ix0 + dx;
      if (ix < 0 || ix > 31) continue;
      float wxv = dx ? wx : 1.f - wx;
      acc += wyv * wxv * img[iy * 32 + ix];
    }
  }
  xs[((size_t)bg * CGC + c) * CNS + p] = acc;
}

// ---------------- K6: k/v = W @ xs + b (16 out-ch per block) ----------------
__global__ void k_kv(const float* __restrict__ xs, const float* __restrict__ Wk,
                     const float* __restrict__ bk, const float* __restrict__ Wv,
                     const float* __restrict__ bv, float* __restrict__ kk,
                     float* __restrict__ vv) {
  int mat = blockIdx.x >> 7;        // 0 = k, 1 = v
  int b   = (blockIdx.x >> 4) & 7;
  int og  = blockIdx.x & 15;
  const float* Wm = mat ? Wv : Wk;
  const float* bm = mat ? bv : bk;
  float* dst = mat ? vv : kk;
  int tid = threadIdx.x;
  __shared__ float wl[CC * 16];
  #pragma unroll
  for (int oo = 0; oo < 16; oo++)
    wl[tid * 16 + oo] = Wm[(size_t)(og * 16 + oo) * CC + tid];
  __syncthreads();
  const float* xb = xs + (size_t)b * CC * CNS + tid * 4;
  float4 acc[16];
  #pragma unroll
  for (int oo = 0; oo < 16; oo++) acc[oo] = make_float4(0.f, 0.f, 0.f, 0.f);
  for (int i = 0; i < CC; i++) {
    float4 xv = *(const float4*)(xb + (size_t)i * CNS);
    const float4* wv4 = (const float4*)(wl + i * 16);
    #pragma unroll
    for (int g4 = 0; g4 < 4; g4++) {
      float4 w4 = wv4[g4];
      acc[g4*4+0].x += w4.x*xv.x; acc[g4*4+0].y += w4.x*xv.y; acc[g4*4+0].z += w4.x*xv.z; acc[g4*4+0].w += w4.x*xv.w;
      acc[g4*4+1].x += w4.y*xv.x; acc[g4*4+1].y += w4.y*xv.y; acc[g4*4+1].z += w4.y*xv.z; acc[g4*4+1].w += w4.y*xv.w;
      acc[g4*4+2].x += w4.z*xv.x; acc[g4*4+2].y += w4.z*xv.y; acc[g4*4+2].z += w4.z*xv.z; acc[g4*4+2].w += w4.z*xv.w;
      acc[g4*4+3].x += w4.w*xv.x; acc[g4*4+3].y += w4.w*xv.y; acc[g4*4+3].z += w4.w*xv.z; acc[g4*4+3].w += w4.w*xv.w;
    }
  }
  #pragma unroll
  for (int oo = 0; oo < 16; oo++) {
    float bb = bm[og * 16 + oo];
    float4 r = acc[oo];
    r.x += bb; r.y += bb; r.z += bb; r.w += bb;
    *(float4*)(dst + ((size_t)(b * CC + og * 16 + oo)) * CNS + tid * 4) = r;
  }
}

// ---------------- K7: flash attention, 1 query row per lane ------------------
__launch_bounds__(256)
__global__ void k_attn(const float* __restrict__ q, const float* __restrict__ kk,
                       const float* __restrict__ vv, float* __restrict__ tmp) {
  int bh   = blockIdx.x >> 3;
  int mblk = blockIdx.x & 7;
  int b = bh >> 3, h = bh & 7;
  int tid = threadIdx.x;
  int lane = tid & 63, wvi = tid >> 6;
  int m = mblk * 256 + wvi * 64 + lane;
  __shared__ float Kt[32 * 36];   // Kt[c*36+n]
  __shared__ float Vt[32 * 36];   // Vt[n*36+c] (transposed)

  float qr[32];
  const float* qp = q + ((size_t)(b * CL + m)) * CC + h * CHC;
  const float scale = 0.17677669529663687f;   // 32^-0.5
  #pragma unroll
  for (int c4 = 0; c4 < 8; c4++) {
    float4 t = *(const float4*)(qp + c4 * 4);
    qr[c4*4+0] = t.x * scale; qr[c4*4+1] = t.y * scale;
    qr[c4*4+2] = t.z * scale; qr[c4*4+3] = t.w * scale;
  }
  float out[32];
  #pragma unroll
  for (int i = 0; i < 32; i++) out[i] = 0.f;
  float mrun = -3.0e38f, lrun = 0.f;

  int sc = tid >> 3;            // staging channel
  int sj = (tid & 7) * 4;       // staging column
  const float* kbase = kk + ((size_t)bh * CHC + sc) * CNS + sj;
  const float* vbase = vv + ((size_t)bh * CHC + sc) * CNS + sj;
  float4 kpre = *(const float4*)(kbase);
  float4 vpre = *(const float4*)(vbase);

  for (int ch = 0; ch < 32; ch++) {
    *(float4*)(Kt + sc * 36 + sj) = kpre;
    Vt[(sj + 0) * 36 + sc] = vpre.x;
    Vt[(sj + 1) * 36 + sc] = vpre.y;
    Vt[(sj + 2) * 36 + sc] = vpre.z;
    Vt[(sj + 3) * 36 + sc] = vpre.w;
    __syncthreads();
    if (ch < 31) {
      kpre = *(const float4*)(kbase + (ch + 1) * 32);
      vpre = *(const float4*)(vbase + (ch + 1) * 32);
    }
    // scores (uniform LDS broadcast reads)
    float s[32];
    #pragma unroll
    for (int i = 0; i < 32; i++) s[i] = 0.f;
    #pragma unroll
    for (int c = 0; c < 32; c++) {
      float qc = qr[c];
      const float4* kr = (const float4*)(Kt + c * 36);
      #pragma unroll
      for (int n4 = 0; n4 < 8; n4++) {
        float4 kv = kr[n4];
        s[n4*4+0] += qc * kv.x; s[n4*4+1] += qc * kv.y;
        s[n4*4+2] += qc * kv.z; s[n4*4+3] += qc * kv.w;
      }
    }
    // per-lane online softmax
    float mc = s[0];
    #pragma unroll
    for (int i = 1; i < 32; i++) mc = fmaxf(mc, s[i]);
    float mnew = fmaxf(mrun, mc);
    float corr = __expf(mrun - mnew);
    lrun *= corr;
    #pragma unroll
    for (int i = 0; i < 32; i++) out[i] *= corr;
    float ps = 0.f;
    #pragma unroll
    for (int i = 0; i < 32; i++) { float pv = __expf(s[i] - mnew); s[i] = pv; ps += pv; }
    lrun += ps;
    mrun = mnew;
    // PV (uniform LDS broadcast reads)
    #pragma unroll
    for (int n = 0; n < 32; n++) {
      float pn = s[n];
      const float4* vr = (const float4*)(Vt + n * 36);
      #pragma unroll
      for (int c4 = 0; c4 < 8; c4++) {
        float4 vx = vr[c4];
        out[c4*4+0] += pn * vx.x; out[c4*4+1] += pn * vx.y;
        out[c4*4+2] += pn * vx.z; out[c4*4+3] += pn * vx.w;
      }
    }
    __syncthreads();
  }
  float rl = 1.f / lrun;
  float* op = tmp + ((size_t)(b * CL + m)) * CC + h * CHC;
  #pragma unroll
  for (int c4 = 0; c4 < 8; c4++) {
    float4 r;
    r.x = out[c4*4+0] * rl; r.y = out[c4*4+1] * rl;
    r.z = out[c4*4+2] * rl; r.w = out[c4*4+3] * rl;
    *(float4*)(op + c4 * 4) = r;
  }
}

// ---------------- K8: y = tmp @ Wo.T + bo (WoT pre-transposed) ---------------
__global__ void k_yproj(const float* __restrict__ tmp, const float* __restrict__ WoT,
                        const float* __restrict__ bo, float* __restrict__ y) {
  int R0 = blockIdx.x * 16;
  int tid = threadIdx.x;   // output channel o
  __shared__ float xl[256 * 20];   // xl[i*20+r]
  for (int idx = tid; idx < 4096; idx += 256) {
    int r = idx >> 8, i = idx & 255;
    xl[i * 20 + r] = tmp[(size_t)(R0 + r) * CC + i];
  }
  __syncthreads();
  float bb = bo[tid];
  float4 acc[4];
  #pragma unroll
  for (int r4 = 0; r4 < 4; r4++) acc[r4] = make_float4(bb, bb, bb, bb);
  for (int i = 0; i < CC; i++) {
    float w = WoT[(size_t)i * CC + tid];
    const float4* xr4 = (const float4*)(xl + i * 20);
    #pragma unroll
    for (int r4 = 0; r4 < 4; r4++) {
      float4 xv = xr4[r4];
      acc[r4].x += w * xv.x; acc[r4].y += w * xv.y;
      acc[r4].z += w * xv.z; acc[r4].w += w * xv.w;
    }
  }
  #pragma unroll
  for (int r4 = 0; r4 < 4; r4++) {
    y[(size_t)(R0 + r4 * 4 + 0) * CC + tid] = acc[r4].x;
    y[(size_t)(R0 + r4 * 4 + 1) * CC + tid] = acc[r4].y;
    y[(size_t)(R0 + r4 * 4 + 2) * CC + tid] = acc[r4].z;
    y[(size_t)(R0 + r4 * 4 + 3) * CC + tid] = acc[r4].w;
  }
}

extern "C" void kernel_launch(void* const* d_in, const int* in_sizes, int n_in,
                              void* d_out, int out_size, void* d_ws, size_t ws_size,
                              hipStream_t stream) {
  const float* x    = (const float*)d_in[0];
  const float* q    = (const float*)d_in[1];
  const float* mask = (const float*)d_in[2];
  const float* Wq   = (const float*)d_in[3];
  const float* bq   = (const float*)d_in[4];
  const float* Wmod = (const float*)d_in[5];
  const float* dw_w = (const float*)d_in[6];
  const float* dw_b = (const float*)d_in[7];
  const float* ln_w = (const float*)d_in[8];
  const float* ln_b = (const float*)d_in[9];
  const float* offw = (const float*)d_in[10];
  const float* Wk   = (const float*)d_in[11];
  const float* bk   = (const float*)d_in[12];
  const float* Wv   = (const float*)d_in[13];
  const float* bv   = (const float*)d_in[14];
  const float* Wo   = (const float*)d_in[15];
  const float* bo   = (const float*)d_in[16];

  float* ws = (float*)d_ws;
  float* out = (float*)d_out;
  float* out_y   = out;
  float* out_pos = out + (size_t)CB * CL * CC;               // 4,194,304
  float* out_ref = out_pos + (size_t)CBG * CHW * 2;          // +131,072

  // zero the atomic accumulators (qpool + msum)
  hipMemsetAsync(d_ws, 0, WS_QCOND * sizeof(float), stream);

  k_pool<<<256, 256, 0, stream>>>(q, mask, ws + WS_QPOOL, ws + WS_MSUM);
  k_qcond<<<8, 256, 0, stream>>>(ws + WS_QPOOL, ws + WS_MSUM, Wq, bq, ws + WS_QCOND);
  k_transpose<<<256, 256, 0, stream>>>(Wo, ws + WS_WOT);
  k_mod<<<128, 256, 0, stream>>>(x, ws + WS_QCOND, Wmod, ws + WS_QT);
  k_off<<<8192, 256, 0, stream>>>(ws + WS_QT, dw_w, dw_b, ln_w, ln_b, offw,
                                  ws + WS_POS, out_pos, out_ref);
  k_sample<<<8192, 256, 0, stream>>>(x, ws + WS_POS, ws + WS_XS);
  k_kv<<<256, 256, 0, stream>>>(ws + WS_XS, Wk, bk, Wv, bv, ws + WS_K, ws + WS_V);
  k_attn<<<512, 256, 0, stream>>>(q, ws + WS_K, ws + WS_V, ws + WS_TMP);
  k_yproj<<<1024, 256, 0, stream>>>(ws + WS_TMP, ws + WS_WOT, bo, out_y);
}

// Round 3
// 339.867 us; speedup vs baseline: 2.5551x; 2.5551x over previous
//
#include <hip/hip_runtime.h>
#include <math.h>

typedef unsigned int uint;
typedef unsigned short ushort;
typedef __attribute__((ext_vector_type(8))) short short8;
typedef __attribute__((ext_vector_type(4))) float f32x4;

// Problem constants
constexpr int CB  = 8;      // batch B
constexpr int CL  = 2048;   // sequence length L
constexpr int CC  = 256;    // channels NC
constexpr int CHC = 32;     // head channels
constexpr int CGC = 32;     // group channels
constexpr int CHW = 1024;   // H*W (32*32)
constexpr int CNS = 1024;   // n_sample
constexpr int CBG = 64;     // B * n_groups

// Workspace layout (floats)
constexpr size_t WS_QPOOL = 0;            // 2048
constexpr size_t WS_MSUM  = 2048;         // 8
constexpr size_t WS_QCOND = 2176;         // 2048
constexpr size_t WS_QT    = 4224;         // 2,097,152 f32 (8,256,32,32); reused as qb bf16 (8,2048,256)
constexpr size_t WS_POS   = 2101376;      // 131,072    (64,32,32,2)
constexpr size_t WS_XS    = 2232448;      // 2,097,152 f32; reused as kb bf16 (64,1024,32) + vb bf16 (64,32,1024)
constexpr size_t WS_K     = 4329600;      // 2,097,152
constexpr size_t WS_V     = 6426752;      // 2,097,152
constexpr size_t WS_TMP   = 8523904;      // 4,194,304  (8,2048,256)
constexpr size_t WS_WOT   = 12718208;     // 65,536

static __device__ __forceinline__ ushort f2bf(float f) {
  uint u = __float_as_uint(f);
  return (ushort)((u + 0x7FFFu + ((u >> 16) & 1u)) >> 16);
}

// ---------------- K1: masked mean pool (partial sums via atomics) -------------
__global__ void k_pool(const float* __restrict__ q, const float* __restrict__ mask,
                       float* __restrict__ qpool, float* __restrict__ msum) {
  int b  = blockIdx.x >> 5;
  int lc = blockIdx.x & 31;
  int l0 = lc * 64;
  int tid = threadIdx.x;
  __shared__ float mloc[64];
  if (tid < 64) mloc[tid] = mask[b * CL + l0 + tid];
  __syncthreads();
  if (tid == 0) {
    float s = 0.f;
    for (int j = 0; j < 64; j++) s += mloc[j];
    atomicAdd(&msum[b], s);
  }
  float acc = 0.f;
  const float* qb = q + (size_t)(b * CL + l0) * CC + tid;
  for (int j = 0; j < 64; j++) acc += qb[(size_t)j * CC] * mloc[j];
  atomicAdd(&qpool[b * CC + tid], acc);
}

// ---------------- K2: q_cond = pooled_mean @ Wq.T + bq ----------------------
__global__ void k_qcond(const float* __restrict__ qpool, const float* __restrict__ msum,
                        const float* __restrict__ Wq, const float* __restrict__ bq,
                        float* __restrict__ qcond) {
  int b = blockIdx.x, o = threadIdx.x;
  __shared__ float qm[CC];
  float inv = 1.f / (msum[b] + 1e-6f);
  qm[o] = qpool[b * CC + o] * inv;
  __syncthreads();
  float acc = bq[o];
  const float* wrow = Wq + (size_t)o * CC;
  for (int i = 0; i < CC; i++) acc += wrow[i] * qm[i];
  qcond[b * CC + o] = acc;
}

// ---------------- K2b: transpose Wo ------------------------------------------
__global__ void k_transpose(const float* __restrict__ Wo, float* __restrict__ WoT) {
  int o = blockIdx.x, i = threadIdx.x;
  WoT[(size_t)i * CC + o] = Wo[(size_t)o * CC + i];
}

// ---------------- K3: modulated 1x1 conv (16 out-ch per block) --------------
__global__ void k_mod(const float* __restrict__ x, const float* __restrict__ qcond,
                      const float* __restrict__ Wmod, float* __restrict__ qt) {
  int b  = blockIdx.x >> 4;
  int og = blockIdx.x & 15;
  int tid = threadIdx.x;
  __shared__ float wl[CC * 16];
  __shared__ float dl[16];
  float qi = qcond[b * CC + tid] + 1.f;
  #pragma unroll
  for (int oo = 0; oo < 16; oo++)
    wl[tid * 16 + oo] = Wmod[(size_t)(og * 16 + oo) * CC + tid] * qi;
  __syncthreads();
  if (tid < 16) {
    float s = 0.f;
    for (int i = 0; i < CC; i++) { float w = wl[i * 16 + tid]; s += w * w; }
    dl[tid] = rsqrtf(s + 1e-8f);
  }
  __syncthreads();
  const float* xb = x + (size_t)(b & 1) * CC * CHW + tid * 4;
  float4 acc[16];
  #pragma unroll
  for (int oo = 0; oo < 16; oo++) acc[oo] = make_float4(0.f, 0.f, 0.f, 0.f);
  for (int i = 0; i < CC; i++) {
    float4 xv = *(const float4*)(xb + (size_t)i * CHW);
    const float4* wv4 = (const float4*)(wl + i * 16);
    #pragma unroll
    for (int g4 = 0; g4 < 4; g4++) {
      float4 w4 = wv4[g4];
      acc[g4*4+0].x += w4.x*xv.x; acc[g4*4+0].y += w4.x*xv.y; acc[g4*4+0].z += w4.x*xv.z; acc[g4*4+0].w += w4.x*xv.w;
      acc[g4*4+1].x += w4.y*xv.x; acc[g4*4+1].y += w4.y*xv.y; acc[g4*4+1].z += w4.y*xv.z; acc[g4*4+1].w += w4.y*xv.w;
      acc[g4*4+2].x += w4.z*xv.x; acc[g4*4+2].y += w4.z*xv.y; acc[g4*4+2].z += w4.z*xv.z; acc[g4*4+2].w += w4.z*xv.w;
      acc[g4*4+3].x += w4.w*xv.x; acc[g4*4+3].y += w4.w*xv.y; acc[g4*4+3].z += w4.w*xv.z; acc[g4*4+3].w += w4.w*xv.w;
    }
  }
  #pragma unroll
  for (int oo = 0; oo < 16; oo++) {
    float d = dl[oo];
    float4 r = acc[oo];
    r.x *= d; r.y *= d; r.z *= d; r.w *= d;
    *(float4*)(qt + ((size_t)(b * CC + og * 16 + oo)) * CHW + tid * 4) = r;
  }
}

// ------- K4: dwconv3x3 + LN + GELU + offset proj + tanh + ref -> pos --------
__global__ void k_off(const float* __restrict__ qt, const float* __restrict__ dww,
                      const float* __restrict__ dwb, const float* __restrict__ lnw,
                      const float* __restrict__ lnb, const float* __restrict__ offw,
                      float* __restrict__ posw, float* __restrict__ out_pos,
                      float* __restrict__ out_ref) {
  int bg   = blockIdx.x >> 7;
  int pblk = blockIdx.x & 127;
  int tid  = threadIdx.x;
  int c = tid & 31, pp = tid >> 5;
  int p0 = pblk * 8;
  int yy = p0 >> 5;
  int xx = (p0 & 31) + pp;
  int p  = p0 + pp;
  const float* src = qt + ((size_t)bg * CGC + c) * CHW;
  float acc = dwb[c];
  #pragma unroll
  for (int ky = 0; ky < 3; ky++) {
    int yr = yy + ky - 1;
    if (yr < 0 || yr > 31) continue;
    #pragma unroll
    for (int kx = 0; kx < 3; kx++) {
      int xc = xx + kx - 1;
      if (xc < 0 || xc > 31) continue;
      acc += dww[c * 9 + ky * 3 + kx] * src[yr * 32 + xc];
    }
  }
  float s1 = acc, s2 = acc * acc;
  #pragma unroll
  for (int m = 1; m < 32; m <<= 1) { s1 += __shfl_xor(s1, m, 32); s2 += __shfl_xor(s2, m, 32); }
  float mu  = s1 * (1.f / 32.f);
  float var = s2 * (1.f / 32.f) - mu * mu;
  float tn  = (acc - mu) * rsqrtf(var + 1e-5f) * lnw[c] + lnb[c];
  float g   = 0.5f * tn * (1.f + erff(tn * 0.70710678118654752f));
  float sy = offw[c] * g, sx = offw[32 + c] * g;
  #pragma unroll
  for (int m = 1; m < 32; m <<= 1) { sy += __shfl_xor(sy, m, 32); sx += __shfl_xor(sx, m, 32); }
  if (c < 2) {
    float v   = (c == 0) ? sy : sx;
    float off = tanhf(v) * (2.f / 31.f);
    float coord = (c == 0) ? (float)yy : (float)xx;
    float ref = (0.5f + coord) * (2.f / 31.f) - 1.f;
    float pv  = off + ref;
    int oidx = bg * 2048 + p * 2 + c;
    posw[oidx]    = pv;
    out_pos[oidx] = pv;
    out_ref[oidx] = ref;
  }
}

// ---------------- K5: bilinear grid sample ----------------------------------
__global__ void k_sample(const float* __restrict__ x, const float* __restrict__ posw,
                         float* __restrict__ xs) {
  int bg   = blockIdx.x >> 7;
  int pblk = blockIdx.x & 127;
  int tid  = threadIdx.x;
  int c = tid >> 3, pp = tid & 7;
  int p = pblk * 8 + pp;
  float py = posw[bg * 2048 + p * 2 + 0];
  float px = posw[bg * 2048 + p * 2 + 1];
  float gx = (px + 1.f) * 15.5f;
  float gy = (py + 1.f) * 15.5f;
  float x0f = floorf(gx), y0f = floorf(gy);
  float wx = gx - x0f, wy = gy - y0f;
  int ix0 = (int)x0f, iy0 = (int)y0f;
  const float* img = x + (size_t)((bg >> 3) & 1) * CC * CHW + ((size_t)((bg & 7) * CGC + c)) * CHW;
  float acc = 0.f;
  #pragma unroll
  for (int dy = 0; dy < 2; dy++) {
    int iy = iy0 + dy;
    if (iy < 0 || iy > 31) continue;
    float wyv = dy ? wy : 1.f - wy;
    #pragma unroll
    for (int dx = 0; dx < 2; dx++) {
      int ix = ix0 + dx;
      if (ix < 0 || ix > 31) continue;
      float wxv = dx ? wx : 1.f - wx;
      acc += wyv * wxv * img[iy * 32 + ix];
    }
  }
  xs[((size_t)bg * CGC + c) * CNS + p] = acc;
}

// ---------------- K6: k/v = W @ xs + b --------------------------------------
__global__ void k_kv(const float* __restrict__ xs, const float* __restrict__ Wk,
                     const float* __restrict__ bk, const float* __restrict__ Wv,
                     const float* __restrict__ bv, float* __restrict__ kk,
                     float* __restrict__ vv) {
  int mat = blockIdx.x >> 7;
  int b   = (blockIdx.x >> 4) & 7;
  int og  = blockIdx.x & 15;
  const float* Wm = mat ? Wv : Wk;
  const float* bm = mat ? bv : bk;
  float* dst = mat ? vv : kk;
  int tid = threadIdx.x;
  __shared__ float wl[CC * 16];
  #pragma unroll
  for (int oo = 0; oo < 16; oo++)
    wl[tid * 16 + oo] = Wm[(size_t)(og * 16 + oo) * CC + tid];
  __syncthreads();
  const float* xb = xs + (size_t)b * CC * CNS + tid * 4;
  float4 acc[16];
  #pragma unroll
  for (int oo = 0; oo < 16; oo++) acc[oo] = make_float4(0.f, 0.f, 0.f, 0.f);
  for (int i = 0; i < CC; i++) {
    float4 xv = *(const float4*)(xb + (size_t)i * CNS);
    const float4* wv4 = (const float4*)(wl + i * 16);
    #pragma unroll
    for (int g4 = 0; g4 < 4; g4++) {
      float4 w4 = wv4[g4];
      acc[g4*4+0].x += w4.x*xv.x; acc[g4*4+0].y += w4.x*xv.y; acc[g4*4+0].z += w4.x*xv.z; acc[g4*4+0].w += w4.x*xv.w;
      acc[g4*4+1].x += w4.y*xv.x; acc[g4*4+1].y += w4.y*xv.y; acc[g4*4+1].z += w4.y*xv.z; acc[g4*4+1].w += w4.y*xv.w;
      acc[g4*4+2].x += w4.z*xv.x; acc[g4*4+2].y += w4.z*xv.y; acc[g4*4+2].z += w4.z*xv.z; acc[g4*4+2].w += w4.z*xv.w;
      acc[g4*4+3].x += w4.w*xv.x; acc[g4*4+3].y += w4.w*xv.y; acc[g4*4+3].z += w4.w*xv.z; acc[g4*4+3].w += w4.w*xv.w;
    }
  }
  #pragma unroll
  for (int oo = 0; oo < 16; oo++) {
    float bb = bm[og * 16 + oo];
    float4 r = acc[oo];
    r.x += bb; r.y += bb; r.z += bb; r.w += bb;
    *(float4*)(dst + ((size_t)(b * CC + og * 16 + oo)) * CNS + tid * 4) = r;
  }
}

// ---------------- K6b: convert q -> bf16, pre-scaled ------------------------
__global__ void k_cvt_q(const float* __restrict__ q, ushort* __restrict__ qb) {
  const float scale = 0.17677669529663687f;
  size_t i0 = ((size_t)blockIdx.x * 256 + threadIdx.x) * 8;
  float4 a = *(const float4*)(q + i0);
  float4 b = *(const float4*)(q + i0 + 4);
  ushort4 r0, r1;
  r0.x = f2bf(a.x * scale); r0.y = f2bf(a.y * scale);
  r0.z = f2bf(a.z * scale); r0.w = f2bf(a.w * scale);
  r1.x = f2bf(b.x * scale); r1.y = f2bf(b.y * scale);
  r1.z = f2bf(b.z * scale); r1.w = f2bf(b.w * scale);
  *(ushort4*)(qb + i0) = r0;
  *(ushort4*)(qb + i0 + 4) = r1;
}

// ---------------- K6c: convert+transpose K: (bh,32,1024) f32 -> (bh,1024,32) bf16
__global__ void k_cvt_k(const float* __restrict__ kk, ushort* __restrict__ kb) {
  int bh = blockIdx.x >> 2;
  int nb = blockIdx.x & 3;
  int tid = threadIdx.x;
  __shared__ float t[32][257];
  const float* src = kk + (size_t)bh * 32768 + nb * 256;
  #pragma unroll 8
  for (int c = 0; c < 32; c++) t[c][tid] = src[(size_t)c * 1024 + tid];
  __syncthreads();
  uint vals[16];
  #pragma unroll
  for (int c2 = 0; c2 < 16; c2++) {
    uint lo = f2bf(t[2 * c2][tid]);
    uint hi = f2bf(t[2 * c2 + 1][tid]);
    vals[c2] = lo | (hi << 16);
  }
  uint* dst = (uint*)(kb + (size_t)bh * 32768 + (size_t)(nb * 256 + tid) * 32);
  uint4* d4 = (uint4*)dst;
  #pragma unroll
  for (int i = 0; i < 4; i++)
    d4[i] = make_uint4(vals[i * 4], vals[i * 4 + 1], vals[i * 4 + 2], vals[i * 4 + 3]);
}

// ---------------- K6d: convert V -> bf16 (layout unchanged) -----------------
__global__ void k_cvt_v(const float* __restrict__ vv, ushort* __restrict__ vb) {
  size_t i0 = ((size_t)blockIdx.x * 256 + threadIdx.x) * 8;
  float4 a = *(const float4*)(vv + i0);
  float4 b = *(const float4*)(vv + i0 + 4);
  ushort4 r0, r1;
  r0.x = f2bf(a.x); r0.y = f2bf(a.y); r0.z = f2bf(a.z); r0.w = f2bf(a.w);
  r1.x = f2bf(b.x); r1.y = f2bf(b.y); r1.z = f2bf(b.z); r1.w = f2bf(b.w);
  *(ushort4*)(vb + i0) = r0;
  *(ushort4*)(vb + i0 + 4) = r1;
}

// ---------------- K7: MFMA flash attention (swapped-operand) -----------------
// Per wave: 16 queries (col=lane&15), iterate 16 chunks of 64 keys.
// S^T = mfma(K_tile, Q_tile): lane holds S[n = ch*64+16f+g*4+r][m = col].
// P staged per-wave in XOR-swizzled LDS, re-read as B-fragments for PV.
// out^T = mfma(V_tile, P^T): lane holds out[c = 16cf+g*4+r][m = col].
__launch_bounds__(256)
__global__ void k_attn_mfma(const ushort* __restrict__ qb, const ushort* __restrict__ kb,
                            const ushort* __restrict__ vb, float* __restrict__ tmp) {
  int bh = blockIdx.x >> 5;          // 64
  int mb = blockIdx.x & 31;          // 32 m-tiles of 64 rows
  int b = bh >> 3, h = bh & 7;
  int tid = threadIdx.x;
  int wid = tid >> 6, lane = tid & 63;
  int col = lane & 15, g = lane >> 4;
  int m = mb * 64 + wid * 16 + col;  // this lane's query row

  __shared__ ushort plds_all[4][1024];   // 2KB per wave, no cross-wave sharing
  char* pw = (char*)&plds_all[wid][0];
  int swz = (col & 7) << 4;

  // Q fragment: B-layout (col=m, k = g*8+j), 8 consecutive bf16 channels
  const ushort* qp = qb + ((size_t)(b * CL + m)) * CC + h * CHC + g * 8;
  short8 qfrag = *(const short8*)qp;

  const ushort* kbase = kb + (size_t)bh * 32768;   // [n][c], n-major
  const ushort* vbase = vb + (size_t)bh * 32768;   // [c][n], c-major

  f32x4 oacc[2] = {{0.f, 0.f, 0.f, 0.f}, {0.f, 0.f, 0.f, 0.f}};
  float mrun = -3.0e38f, lrun = 0.f;

  for (int ch = 0; ch < 16; ch++) {
    // ---- K fragments (A-layout: row=n local=col, k=c=g*8+j) ----
    short8 kf0 = *(const short8*)(kbase + (size_t)(ch * 64 +  0 + col) * 32 + g * 8);
    short8 kf1 = *(const short8*)(kbase + (size_t)(ch * 64 + 16 + col) * 32 + g * 8);
    short8 kf2 = *(const short8*)(kbase + (size_t)(ch * 64 + 32 + col) * 32 + g * 8);
    short8 kf3 = *(const short8*)(kbase + (size_t)(ch * 64 + 48 + col) * 32 + g * 8);
    // ---- V fragments (A-layout: row=c local=col, k=n=g*8+j) ----
    short8 vf00 = *(const short8*)(vbase + (size_t)(col     ) * 1024 + ch * 64 +  0 + g * 8);
    short8 vf01 = *(const short8*)(vbase + (size_t)(col     ) * 1024 + ch * 64 + 32 + g * 8);
    short8 vf10 = *(const short8*)(vbase + (size_t)(col + 16) * 1024 + ch * 64 +  0 + g * 8);
    short8 vf11 = *(const short8*)(vbase + (size_t)(col + 16) * 1024 + ch * 64 + 32 + g * 8);

    f32x4 zero = {0.f, 0.f, 0.f, 0.f};
    f32x4 s0 = __builtin_amdgcn_mfma_f32_16x16x32_bf16(kf0, qfrag, zero, 0, 0, 0);
    f32x4 s1 = __builtin_amdgcn_mfma_f32_16x16x32_bf16(kf1, qfrag, zero, 0, 0, 0);
    f32x4 s2 = __builtin_amdgcn_mfma_f32_16x16x32_bf16(kf2, qfrag, zero, 0, 0, 0);
    f32x4 s3 = __builtin_amdgcn_mfma_f32_16x16x32_bf16(kf3, qfrag, zero, 0, 0, 0);

    // ---- online softmax (per query m = col; combine the 4 g-groups) ----
    float cmax = s0[0];
    #pragma unroll
    for (int r = 1; r < 4; r++) cmax = fmaxf(cmax, s0[r]);
    #pragma unroll
    for (int r = 0; r < 4; r++) cmax = fmaxf(cmax, s1[r]);
    #pragma unroll
    for (int r = 0; r < 4; r++) cmax = fmaxf(cmax, s2[r]);
    #pragma unroll
    for (int r = 0; r < 4; r++) cmax = fmaxf(cmax, s3[r]);
    cmax = fmaxf(cmax, __shfl_xor(cmax, 16));
    cmax = fmaxf(cmax, __shfl_xor(cmax, 32));
    float mnew = fmaxf(mrun, cmax);
    float corr = __expf(mrun - mnew);
    lrun *= corr;
    #pragma unroll
    for (int r = 0; r < 4; r++) { oacc[0][r] *= corr; oacc[1][r] *= corr; }
    mrun = mnew;

    float psum = 0.f;
    ushort pb[16];
    #pragma unroll
    for (int r = 0; r < 4; r++) { float p = __expf(s0[r] - mnew); psum += p; pb[ 0 + r] = f2bf(p); }
    #pragma unroll
    for (int r = 0; r < 4; r++) { float p = __expf(s1[r] - mnew); psum += p; pb[ 4 + r] = f2bf(p); }
    #pragma unroll
    for (int r = 0; r < 4; r++) { float p = __expf(s2[r] - mnew); psum += p; pb[ 8 + r] = f2bf(p); }
    #pragma unroll
    for (int r = 0; r < 4; r++) { float p = __expf(s3[r] - mnew); psum += p; pb[12 + r] = f2bf(p); }
    lrun += psum;

    // ---- stage P[m][n] (row m=col, 64 n per row), XOR-swizzled ----
    #pragma unroll
    for (int f = 0; f < 4; f++) {
      uint lo = (uint)pb[f * 4 + 0] | ((uint)pb[f * 4 + 1] << 16);
      uint hi = (uint)pb[f * 4 + 2] | ((uint)pb[f * 4 + 3] << 16);
      *(uint2*)(pw + (((col * 128) + (g * 8) + (f * 32)) ^ swz)) = make_uint2(lo, hi);
    }
    // ---- re-read as B-fragments (col=m, k=n= kc*32+g*8+j) ----
    short8 pf0 = *(const short8*)(pw + (((col * 128) +  0 + (g * 16)) ^ swz));
    short8 pf1 = *(const short8*)(pw + (((col * 128) + 64 + (g * 16)) ^ swz));

    oacc[0] = __builtin_amdgcn_mfma_f32_16x16x32_bf16(vf00, pf0, oacc[0], 0, 0, 0);
    oacc[0] = __builtin_amdgcn_mfma_f32_16x16x32_bf16(vf01, pf1, oacc[0], 0, 0, 0);
    oacc[1] = __builtin_amdgcn_mfma_f32_16x16x32_bf16(vf10, pf0, oacc[1], 0, 0, 0);
    oacc[1] = __builtin_amdgcn_mfma_f32_16x16x32_bf16(vf11, pf1, oacc[1], 0, 0, 0);
  }

  lrun += __shfl_xor(lrun, 16);
  lrun += __shfl_xor(lrun, 32);
  float rl = 1.f / lrun;

  // out^T: lane holds c = 16*cf + g*4 + r for query m=col
  float* op = tmp + ((size_t)(b * CL + m)) * CC + h * CHC;
  #pragma unroll
  for (int cf = 0; cf < 2; cf++) {
    float4 st;
    st.x = oacc[cf][0] * rl; st.y = oacc[cf][1] * rl;
    st.z = oacc[cf][2] * rl; st.w = oacc[cf][3] * rl;
    *(float4*)(op + cf * 16 + g * 4) = st;
  }
}

// ---------------- K8: y = tmp @ Wo.T + bo -----------------------------------
__global__ void k_yproj(const float* __restrict__ tmp, const float* __restrict__ WoT,
                        const float* __restrict__ bo, float* __restrict__ y) {
  int R0 = blockIdx.x * 16;
  int tid = threadIdx.x;
  __shared__ float xl[256 * 20];
  for (int idx = tid; idx < 4096; idx += 256) {
    int r = idx >> 8, i = idx & 255;
    xl[i * 20 + r] = tmp[(size_t)(R0 + r) * CC + i];
  }
  __syncthreads();
  float bb = bo[tid];
  float4 acc[4];
  #pragma unroll
  for (int r4 = 0; r4 < 4; r4++) acc[r4] = make_float4(bb, bb, bb, bb);
  for (int i = 0; i < CC; i++) {
    float w = WoT[(size_t)i * CC + tid];
    const float4* xr4 = (const float4*)(xl + i * 20);
    #pragma unroll
    for (int r4 = 0; r4 < 4; r4++) {
      float4 xv = xr4[r4];
      acc[r4].x += w * xv.x; acc[r4].y += w * xv.y;
      acc[r4].z += w * xv.z; acc[r4].w += w * xv.w;
    }
  }
  #pragma unroll
  for (int r4 = 0; r4 < 4; r4++) {
    y[(size_t)(R0 + r4 * 4 + 0) * CC + tid] = acc[r4].x;
    y[(size_t)(R0 + r4 * 4 + 1) * CC + tid] = acc[r4].y;
    y[(size_t)(R0 + r4 * 4 + 2) * CC + tid] = acc[r4].z;
    y[(size_t)(R0 + r4 * 4 + 3) * CC + tid] = acc[r4].w;
  }
}

extern "C" void kernel_launch(void* const* d_in, const int* in_sizes, int n_in,
                              void* d_out, int out_size, void* d_ws, size_t ws_size,
                              hipStream_t stream) {
  const float* x    = (const float*)d_in[0];
  const float* q    = (const float*)d_in[1];
  const float* mask = (const float*)d_in[2];
  const float* Wq   = (const float*)d_in[3];
  const float* bq   = (const float*)d_in[4];
  const float* Wmod = (const float*)d_in[5];
  const float* dw_w = (const float*)d_in[6];
  const float* dw_b = (const float*)d_in[7];
  const float* ln_w = (const float*)d_in[8];
  const float* ln_b = (const float*)d_in[9];
  const float* offw = (const float*)d_in[10];
  const float* Wk   = (const float*)d_in[11];
  const float* bk   = (const float*)d_in[12];
  const float* Wv   = (const float*)d_in[13];
  const float* bv   = (const float*)d_in[14];
  const float* Wo   = (const float*)d_in[15];
  const float* bo   = (const float*)d_in[16];

  float* ws = (float*)d_ws;
  float* out = (float*)d_out;
  float* out_y   = out;
  float* out_pos = out + (size_t)CB * CL * CC;
  float* out_ref = out_pos + (size_t)CBG * CHW * 2;

  // bf16 views over dead f32 regions (qb over QT after k_off; kb/vb over XS after k_kv)
  ushort* qbuf = (ushort*)(ws + WS_QT);
  ushort* kbuf = (ushort*)(ws + WS_XS);
  ushort* vbuf = (ushort*)(ws + WS_XS + 1048576);

  hipMemsetAsync(d_ws, 0, WS_QCOND * sizeof(float), stream);

  k_pool<<<256, 256, 0, stream>>>(q, mask, ws + WS_QPOOL, ws + WS_MSUM);
  k_qcond<<<8, 256, 0, stream>>>(ws + WS_QPOOL, ws + WS_MSUM, Wq, bq, ws + WS_QCOND);
  k_transpose<<<256, 256, 0, stream>>>(Wo, ws + WS_WOT);
  k_mod<<<128, 256, 0, stream>>>(x, ws + WS_QCOND, Wmod, ws + WS_QT);
  k_off<<<8192, 256, 0, stream>>>(ws + WS_QT, dw_w, dw_b, ln_w, ln_b, offw,
                                  ws + WS_POS, out_pos, out_ref);
  k_cvt_q<<<2048, 256, 0, stream>>>(q, qbuf);          // overwrites QT (dead after k_off)
  k_sample<<<8192, 256, 0, stream>>>(x, ws + WS_POS, ws + WS_XS);
  k_kv<<<256, 256, 0, stream>>>(ws + WS_XS, Wk, bk, Wv, bv, ws + WS_K, ws + WS_V);
  k_cvt_k<<<256, 256, 0, stream>>>(ws + WS_K, kbuf);   // overwrites XS (dead after k_kv)
  k_cvt_v<<<1024, 256, 0, stream>>>(ws + WS_V, vbuf);
  k_attn_mfma<<<2048, 256, 0, stream>>>(qbuf, kbuf, vbuf, ws + WS_TMP);
  k_yproj<<<1024, 256, 0, stream>>>(ws + WS_TMP, ws + WS_WOT, bo, out_y);
}

// Round 4
// 293.543 us; speedup vs baseline: 2.9583x; 1.1578x over previous
//
#include <hip/hip_runtime.h>
#include <math.h>

typedef unsigned int uint;
typedef unsigned short ushort;
typedef __attribute__((ext_vector_type(8))) short short8;
typedef __attribute__((ext_vector_type(4))) float f32x4;

// Problem constants
constexpr int CB  = 8;      // batch B
constexpr int CL  = 2048;   // sequence length L
constexpr int CC  = 256;    // channels NC
constexpr int CHC = 32;     // head channels
constexpr int CGC = 32;     // group channels
constexpr int CHW = 1024;   // H*W (32*32)
constexpr int CNS = 1024;   // n_sample
constexpr int CBG = 64;     // B * n_groups

// Workspace layout (float offsets)
constexpr size_t WS_QPOOL = 0;            // 2048
constexpr size_t WS_MSUM  = 2048;         // 8
constexpr size_t WS_QCOND = 2176;         // 2048
constexpr size_t WS_QT    = 4224;         // 2,097,152 f32 (8,256,32,32); reused as qb bf16 (8,2048,256)
constexpr size_t WS_POS   = 2101376;      // 131,072   (64,32,32,2)
constexpr size_t WS_XS    = 2232448;      // region: xs_t bf16 (8,1024,256) = 2M ushort
constexpr size_t WS_K     = 4329600;      // region: kb bf16 (64,1024,32) + vb bf16 (64,32,1024)
constexpr size_t WS_V     = 6426752;      // region: Wk_bf, Wv_bf, Wo_bf (3 x 65536 ushort)
constexpr size_t WS_TMP   = 8523904;      // region: tmp bf16 (8,2048,256) = 4M ushort

static __device__ __forceinline__ ushort f2bf(float f) {
  uint u = __float_as_uint(f);
  return (ushort)((u + 0x7FFFu + ((u >> 16) & 1u)) >> 16);
}
static __device__ __forceinline__ uint pack2bf(float a, float b) {
  return (uint)f2bf(a) | ((uint)f2bf(b) << 16);
}

// ---------------- K1: masked mean pool (partial sums via atomics) -------------
__global__ void k_pool(const float* __restrict__ q, const float* __restrict__ mask,
                       float* __restrict__ qpool, float* __restrict__ msum) {
  int b  = blockIdx.x >> 5;
  int lc = blockIdx.x & 31;
  int l0 = lc * 64;
  int tid = threadIdx.x;
  __shared__ float mloc[64];
  if (tid < 64) mloc[tid] = mask[b * CL + l0 + tid];
  __syncthreads();
  if (tid == 0) {
    float s = 0.f;
    for (int j = 0; j < 64; j++) s += mloc[j];
    atomicAdd(&msum[b], s);
  }
  float acc = 0.f;
  const float* qb = q + (size_t)(b * CL + l0) * CC + tid;
  for (int j = 0; j < 64; j++) acc += qb[(size_t)j * CC] * mloc[j];
  atomicAdd(&qpool[b * CC + tid], acc);
}

// ---------------- K2: q_cond = pooled_mean @ Wq.T + bq ----------------------
__global__ void k_qcond(const float* __restrict__ qpool, const float* __restrict__ msum,
                        const float* __restrict__ Wq, const float* __restrict__ bq,
                        float* __restrict__ qcond) {
  int b = blockIdx.x, o = threadIdx.x;
  __shared__ float qm[CC];
  float inv = 1.f / (msum[b] + 1e-6f);
  qm[o] = qpool[b * CC + o] * inv;
  __syncthreads();
  float acc = bq[o];
  const float* wrow = Wq + (size_t)o * CC;
  for (int i = 0; i < CC; i++) acc += wrow[i] * qm[i];
  qcond[b * CC + o] = acc;
}

// ---------------- K3: modulated 1x1 conv (16 out-ch per block) --------------
__global__ void k_mod(const float* __restrict__ x, const float* __restrict__ qcond,
                      const float* __restrict__ Wmod, float* __restrict__ qt) {
  int b  = blockIdx.x >> 4;
  int og = blockIdx.x & 15;
  int tid = threadIdx.x;
  __shared__ float wl[CC * 16];
  __shared__ float dl[16];
  float qi = qcond[b * CC + tid] + 1.f;
  #pragma unroll
  for (int oo = 0; oo < 16; oo++)
    wl[tid * 16 + oo] = Wmod[(size_t)(og * 16 + oo) * CC + tid] * qi;
  __syncthreads();
  if (tid < 16) {
    float s = 0.f;
    for (int i = 0; i < CC; i++) { float w = wl[i * 16 + tid]; s += w * w; }
    dl[tid] = rsqrtf(s + 1e-8f);
  }
  __syncthreads();
  const float* xb = x + (size_t)(b & 1) * CC * CHW + tid * 4;
  float4 acc[16];
  #pragma unroll
  for (int oo = 0; oo < 16; oo++) acc[oo] = make_float4(0.f, 0.f, 0.f, 0.f);
  for (int i = 0; i < CC; i++) {
    float4 xv = *(const float4*)(xb + (size_t)i * CHW);
    const float4* wv4 = (const float4*)(wl + i * 16);
    #pragma unroll
    for (int g4 = 0; g4 < 4; g4++) {
      float4 w4 = wv4[g4];
      acc[g4*4+0].x += w4.x*xv.x; acc[g4*4+0].y += w4.x*xv.y; acc[g4*4+0].z += w4.x*xv.z; acc[g4*4+0].w += w4.x*xv.w;
      acc[g4*4+1].x += w4.y*xv.x; acc[g4*4+1].y += w4.y*xv.y; acc[g4*4+1].z += w4.y*xv.z; acc[g4*4+1].w += w4.y*xv.w;
      acc[g4*4+2].x += w4.z*xv.x; acc[g4*4+2].y += w4.z*xv.y; acc[g4*4+2].z += w4.z*xv.z; acc[g4*4+2].w += w4.z*xv.w;
      acc[g4*4+3].x += w4.w*xv.x; acc[g4*4+3].y += w4.w*xv.y; acc[g4*4+3].z += w4.w*xv.z; acc[g4*4+3].w += w4.w*xv.w;
    }
  }
  #pragma unroll
  for (int oo = 0; oo < 16; oo++) {
    float d = dl[oo];
    float4 r = acc[oo];
    r.x *= d; r.y *= d; r.z *= d; r.w *= d;
    *(float4*)(qt + ((size_t)(b * CC + og * 16 + oo)) * CHW + tid * 4) = r;
  }
}

// ------- K4: dwconv3x3 + LN + GELU + offset proj + tanh + ref -> pos --------
__global__ void k_off(const float* __restrict__ qt, const float* __restrict__ dww,
                      const float* __restrict__ dwb, const float* __restrict__ lnw,
                      const float* __restrict__ lnb, const float* __restrict__ offw,
                      float* __restrict__ posw, float* __restrict__ out_pos,
                      float* __restrict__ out_ref) {
  int bg   = blockIdx.x >> 7;
  int pblk = blockIdx.x & 127;
  int tid  = threadIdx.x;
  int c = tid & 31, pp = tid >> 5;
  int p0 = pblk * 8;
  int yy = p0 >> 5;
  int xx = (p0 & 31) + pp;
  int p  = p0 + pp;
  const float* src = qt + ((size_t)bg * CGC + c) * CHW;
  float acc = dwb[c];
  #pragma unroll
  for (int ky = 0; ky < 3; ky++) {
    int yr = yy + ky - 1;
    if (yr < 0 || yr > 31) continue;
    #pragma unroll
    for (int kx = 0; kx < 3; kx++) {
      int xc = xx + kx - 1;
      if (xc < 0 || xc > 31) continue;
      acc += dww[c * 9 + ky * 3 + kx] * src[yr * 32 + xc];
    }
  }
  float s1 = acc, s2 = acc * acc;
  #pragma unroll
  for (int m = 1; m < 32; m <<= 1) { s1 += __shfl_xor(s1, m, 32); s2 += __shfl_xor(s2, m, 32); }
  float mu  = s1 * (1.f / 32.f);
  float var = s2 * (1.f / 32.f) - mu * mu;
  float tn  = (acc - mu) * rsqrtf(var + 1e-5f) * lnw[c] + lnb[c];
  float g   = 0.5f * tn * (1.f + erff(tn * 0.70710678118654752f));
  float sy = offw[c] * g, sx = offw[32 + c] * g;
  #pragma unroll
  for (int m = 1; m < 32; m <<= 1) { sy += __shfl_xor(sy, m, 32); sx += __shfl_xor(sx, m, 32); }
  if (c < 2) {
    float v   = (c == 0) ? sy : sx;
    float off = tanhf(v) * (2.f / 31.f);
    float coord = (c == 0) ? (float)yy : (float)xx;
    float ref = (0.5f + coord) * (2.f / 31.f) - 1.f;
    float pv  = off + ref;
    int oidx = bg * 2048 + p * 2 + c;
    posw[oidx]    = pv;
    out_pos[oidx] = pv;
    out_ref[oidx] = ref;
  }
}

// ---------------- K5: bilinear grid sample -> xs^T bf16 [b][n][i] -----------
__global__ void k_sample(const float* __restrict__ x, const float* __restrict__ posw,
                         ushort* __restrict__ xst) {
  int bg   = blockIdx.x >> 7;
  int pblk = blockIdx.x & 127;
  int tid  = threadIdx.x;
  int c = tid & 31, pp = tid >> 5;      // c fast -> coalesced writes
  int p = pblk * 8 + pp;
  float py = posw[bg * 2048 + p * 2 + 0];
  float px = posw[bg * 2048 + p * 2 + 1];
  float gx = (px + 1.f) * 15.5f;
  float gy = (py + 1.f) * 15.5f;
  float x0f = floorf(gx), y0f = floorf(gy);
  float wx = gx - x0f, wy = gy - y0f;
  int ix0 = (int)x0f, iy0 = (int)y0f;
  const float* img = x + (size_t)((bg >> 3) & 1) * CC * CHW + ((size_t)((bg & 7) * CGC + c)) * CHW;
  float acc = 0.f;
  #pragma unroll
  for (int dy = 0; dy < 2; dy++) {
    int iy = iy0 + dy;
    if (iy < 0 || iy > 31) continue;
    float wyv = dy ? wy : 1.f - wy;
    #pragma unroll
    for (int dx = 0; dx < 2; dx++) {
      int ix = ix0 + dx;
      if (ix < 0 || ix > 31) continue;
      float wxv = dx ? wx : 1.f - wx;
      acc += wyv * wxv * img[iy * 32 + ix];
    }
  }
  // xs^T[b][n=p][i = g*32+c]
  xst[((size_t)((bg >> 3) * CNS) + p) * CC + (bg & 7) * CGC + c] = f2bf(acc);
}

// ---------------- K5b: convert Wk/Wv/Wo -> bf16 (row-major preserved) -------
__global__ void k_cvt_w(const float* __restrict__ Wk, const float* __restrict__ Wv,
                        const float* __restrict__ Wo, ushort* __restrict__ wb) {
  int t = blockIdx.x * 256 + threadIdx.x;       // 96 blocks -> 24576 threads
  int which = t >> 13;                          // 8192 threads per 65536-elem matrix
  size_t off = ((size_t)(t & 8191)) * 8;
  const float* src = (which == 0) ? Wk : (which == 1) ? Wv : Wo;
  float4 a = *(const float4*)(src + off);
  float4 b = *(const float4*)(src + off + 4);
  uint4 r;
  r.x = pack2bf(a.x, a.y); r.y = pack2bf(a.z, a.w);
  r.z = pack2bf(b.x, b.y); r.w = pack2bf(b.z, b.w);
  *(uint4*)(wb + (size_t)which * 65536 + off) = r;
}

// ---------------- K6: fused K/V projection via MFMA -------------------------
// K: D[o][n] = mfma(A=Wk row-major, B=xs^T)   -> kb[bh][n][c]
// V: D[n][o] = mfma(A=xs^T,        B=Wv row-major) -> vb[bh][c][n]
// Both operands share the identical [outer=lane&15][k contiguous] fragment.
__launch_bounds__(256)
__global__ void k_kv_mfma(const ushort* __restrict__ xst, const ushort* __restrict__ wkb,
                          const ushort* __restrict__ wvb, const float* __restrict__ bk,
                          const float* __restrict__ bv, ushort* __restrict__ kb,
                          ushort* __restrict__ vb) {
  int tid = threadIdx.x;
  int wid = tid >> 6, lane = tid & 63;
  int widx = blockIdx.x * 4 + wid;       // 8192 waves
  int b  = widx >> 10;
  int nt = (widx >> 4) & 63;
  int ot = widx & 15;
  int col = lane & 15, g = lane >> 4;
  int N0 = nt * 16, O0 = ot * 16;

  const ushort* xsb = xst + ((size_t)(b * CNS + N0 + col)) * CC + g * 8;
  const ushort* wkp = wkb + (size_t)(O0 + col) * CC + g * 8;
  const ushort* wvp = wvb + (size_t)(O0 + col) * CC + g * 8;

  f32x4 ka, va;
  #pragma unroll
  for (int r = 0; r < 4; r++) ka[r] = bk[O0 + g * 4 + r];
  float bvv = bv[O0 + col];
  #pragma unroll
  for (int r = 0; r < 4; r++) va[r] = bvv;

  #pragma unroll
  for (int ks = 0; ks < 8; ks++) {
    short8 xf = *(const short8*)(xsb + ks * 32);
    short8 kf = *(const short8*)(wkp + ks * 32);
    short8 vf = *(const short8*)(wvp + ks * 32);
    ka = __builtin_amdgcn_mfma_f32_16x16x32_bf16(kf, xf, ka, 0, 0, 0);
    va = __builtin_amdgcn_mfma_f32_16x16x32_bf16(xf, vf, va, 0, 0, 0);
  }

  // K store: o = O0+g*4+r (4 consecutive c), n = N0+col
  {
    int hh = O0 >> 5;
    int c0 = (O0 & 31) + g * 4;
    uint2 w;
    w.x = pack2bf(ka[0], ka[1]);
    w.y = pack2bf(ka[2], ka[3]);
    *(uint2*)(kb + ((size_t)((b * 8 + hh) * CNS + N0 + col)) * CHC + c0) = w;
  }
  // V store: n = N0+g*4+r (4 consecutive n), o = O0+col
  {
    int o = O0 + col;
    int hh = o >> 5;
    uint2 w;
    w.x = pack2bf(va[0], va[1]);
    w.y = pack2bf(va[2], va[3]);
    *(uint2*)(vb + ((size_t)((b * 8 + hh) * CHC + (o & 31))) * CNS + N0 + g * 4) = w;
  }
}

// ---------------- K6b: convert q -> bf16, pre-scaled ------------------------
__global__ void k_cvt_q(const float* __restrict__ q, ushort* __restrict__ qb) {
  const float scale = 0.17677669529663687f;
  size_t i0 = ((size_t)blockIdx.x * 256 + threadIdx.x) * 8;
  float4 a = *(const float4*)(q + i0);
  float4 b = *(const float4*)(q + i0 + 4);
  uint4 r;
  r.x = pack2bf(a.x * scale, a.y * scale);
  r.y = pack2bf(a.z * scale, a.w * scale);
  r.z = pack2bf(b.x * scale, b.y * scale);
  r.w = pack2bf(b.z * scale, b.w * scale);
  *(uint4*)(qb + i0) = r;
}

// ---------------- K7: MFMA flash attention, streaming softmax ----------------
__launch_bounds__(256)
__global__ void k_attn_mfma(const ushort* __restrict__ qb, const ushort* __restrict__ kb,
                            const ushort* __restrict__ vb, ushort* __restrict__ tmpb) {
  int bh = blockIdx.x >> 5;
  int mb = blockIdx.x & 31;
  int b = bh >> 3, h = bh & 7;
  int tid = threadIdx.x;
  int wid = tid >> 6, lane = tid & 63;
  int col = lane & 15, g = lane >> 4;
  int m = mb * 64 + wid * 16 + col;

  __shared__ ushort plds_all[4][1024];
  char* pw = (char*)&plds_all[wid][0];
  int swz = (col & 7) << 4;

  const ushort* qp = qb + ((size_t)(b * CL + m)) * CC + h * CHC + g * 8;
  short8 qfrag = *(const short8*)qp;

  const ushort* kbase = kb + (size_t)bh * 32768;   // [n][c]
  const ushort* vbase = vb + (size_t)bh * 32768;   // [c][n]

  f32x4 oacc[2] = {{0.f, 0.f, 0.f, 0.f}, {0.f, 0.f, 0.f, 0.f}};
  float lrun = 0.f;

  for (int ch = 0; ch < 16; ch++) {
    short8 kf0 = *(const short8*)(kbase + (size_t)(ch * 64 +  0 + col) * 32 + g * 8);
    short8 kf1 = *(const short8*)(kbase + (size_t)(ch * 64 + 16 + col) * 32 + g * 8);
    short8 kf2 = *(const short8*)(kbase + (size_t)(ch * 64 + 32 + col) * 32 + g * 8);
    short8 kf3 = *(const short8*)(kbase + (size_t)(ch * 64 + 48 + col) * 32 + g * 8);
    short8 vf00 = *(const short8*)(vbase + (size_t)(col     ) * 1024 + ch * 64 +  0 + g * 8);
    short8 vf01 = *(const short8*)(vbase + (size_t)(col     ) * 1024 + ch * 64 + 32 + g * 8);
    short8 vf10 = *(const short8*)(vbase + (size_t)(col + 16) * 1024 + ch * 64 +  0 + g * 8);
    short8 vf11 = *(const short8*)(vbase + (size_t)(col + 16) * 1024 + ch * 64 + 32 + g * 8);

    f32x4 zero = {0.f, 0.f, 0.f, 0.f};
    f32x4 s0 = __builtin_amdgcn_mfma_f32_16x16x32_bf16(kf0, qfrag, zero, 0, 0, 0);
    f32x4 s1 = __builtin_amdgcn_mfma_f32_16x16x32_bf16(kf1, qfrag, zero, 0, 0, 0);
    f32x4 s2 = __builtin_amdgcn_mfma_f32_16x16x32_bf16(kf2, qfrag, zero, 0, 0, 0);
    f32x4 s3 = __builtin_amdgcn_mfma_f32_16x16x32_bf16(kf3, qfrag, zero, 0, 0, 0);

    // streaming exp-sum (softmax is shift-invariant; scores bounded, no overflow)
    float psum = 0.f;
    ushort pb[16];
    #pragma unroll
    for (int r = 0; r < 4; r++) { float p = __expf(s0[r]); psum += p; pb[ 0 + r] = f2bf(p); }
    #pragma unroll
    for (int r = 0; r < 4; r++) { float p = __expf(s1[r]); psum += p; pb[ 4 + r] = f2bf(p); }
    #pragma unroll
    for (int r = 0; r < 4; r++) { float p = __expf(s2[r]); psum += p; pb[ 8 + r] = f2bf(p); }
    #pragma unroll
    for (int r = 0; r < 4; r++) { float p = __expf(s3[r]); psum += p; pb[12 + r] = f2bf(p); }
    lrun += psum;

    #pragma unroll
    for (int f = 0; f < 4; f++) {
      uint lo = (uint)pb[f * 4 + 0] | ((uint)pb[f * 4 + 1] << 16);
      uint hi = (uint)pb[f * 4 + 2] | ((uint)pb[f * 4 + 3] << 16);
      *(uint2*)(pw + (((col * 128) + (g * 8) + (f * 32)) ^ swz)) = make_uint2(lo, hi);
    }
    short8 pf0 = *(const short8*)(pw + (((col * 128) +  0 + (g * 16)) ^ swz));
    short8 pf1 = *(const short8*)(pw + (((col * 128) + 64 + (g * 16)) ^ swz));

    oacc[0] = __builtin_amdgcn_mfma_f32_16x16x32_bf16(vf00, pf0, oacc[0], 0, 0, 0);
    oacc[0] = __builtin_amdgcn_mfma_f32_16x16x32_bf16(vf01, pf1, oacc[0], 0, 0, 0);
    oacc[1] = __builtin_amdgcn_mfma_f32_16x16x32_bf16(vf10, pf0, oacc[1], 0, 0, 0);
    oacc[1] = __builtin_amdgcn_mfma_f32_16x16x32_bf16(vf11, pf1, oacc[1], 0, 0, 0);
  }

  lrun += __shfl_xor(lrun, 16);
  lrun += __shfl_xor(lrun, 32);
  float rl = 1.f / lrun;

  ushort* op = tmpb + ((size_t)(b * CL + m)) * CC + h * CHC;
  #pragma unroll
  for (int cf = 0; cf < 2; cf++) {
    uint2 w;
    w.x = pack2bf(oacc[cf][0] * rl, oacc[cf][1] * rl);
    w.y = pack2bf(oacc[cf][2] * rl, oacc[cf][3] * rl);
    *(uint2*)(op + cf * 16 + g * 4) = w;
  }
}

// ---------------- K8: y = tmp_bf @ Wo_bf^T + bo via MFMA --------------------
__launch_bounds__(256)
__global__ void k_yproj_mfma(const ushort* __restrict__ tmpb, const ushort* __restrict__ wob,
                             const float* __restrict__ bo, float* __restrict__ y) {
  int tid = threadIdx.x;
  int wid = tid >> 6, lane = tid & 63;
  int widx = blockIdx.x * 4 + wid;      // 16384 waves
  int rt = widx >> 4;                   // 1024 row tiles
  int ot = widx & 15;
  int col = lane & 15, g = lane >> 4;
  int R0 = rt * 16, O0 = ot * 16;

  const ushort* ap = tmpb + ((size_t)(R0 + col)) * CC + g * 8;
  const ushort* bp = wob + (size_t)(O0 + col) * CC + g * 8;

  f32x4 acc;
  float bb = bo[O0 + col];
  #pragma unroll
  for (int r = 0; r < 4; r++) acc[r] = bb;

  #pragma unroll
  for (int ks = 0; ks < 8; ks++) {
    short8 af = *(const short8*)(ap + ks * 32);
    short8 bf = *(const short8*)(bp + ks * 32);
    acc = __builtin_amdgcn_mfma_f32_16x16x32_bf16(af, bf, acc, 0, 0, 0);
  }

  // D[r][o]: row = R0+g*4+reg, col = O0+(lane&15)
  #pragma unroll
  for (int r = 0; r < 4; r++)
    y[(size_t)(R0 + g * 4 + r) * CC + O0 + col] = acc[r];
}

extern "C" void kernel_launch(void* const* d_in, const int* in_sizes, int n_in,
                              void* d_out, int out_size, void* d_ws, size_t ws_size,
                              hipStream_t stream) {
  const float* x    = (const float*)d_in[0];
  const float* q    = (const float*)d_in[1];
  const float* mask = (const float*)d_in[2];
  const float* Wq   = (const float*)d_in[3];
  const float* bq   = (const float*)d_in[4];
  const float* Wmod = (const float*)d_in[5];
  const float* dw_w = (const float*)d_in[6];
  const float* dw_b = (const float*)d_in[7];
  const float* ln_w = (const float*)d_in[8];
  const float* ln_b = (const float*)d_in[9];
  const float* offw = (const float*)d_in[10];
  const float* Wk   = (const float*)d_in[11];
  const float* bk   = (const float*)d_in[12];
  const float* Wv   = (const float*)d_in[13];
  const float* bv   = (const float*)d_in[14];
  const float* Wo   = (const float*)d_in[15];
  const float* bo   = (const float*)d_in[16];

  float* ws = (float*)d_ws;
  float* out = (float*)d_out;
  float* out_y   = out;
  float* out_pos = out + (size_t)CB * CL * CC;
  float* out_ref = out_pos + (size_t)CBG * CHW * 2;

  ushort* qbuf = (ushort*)(ws + WS_QT);                 // bf16 q (pre-scaled), over QT after k_off
  ushort* xst  = (ushort*)(ws + WS_XS);                 // bf16 xs^T [8][1024][256]
  ushort* kbuf = (ushort*)(ws + WS_K);                  // bf16 kb [64][1024][32]
  ushort* vbuf = (ushort*)(ws + WS_K + 1048576);        // bf16 vb [64][32][1024]
  ushort* wkb  = (ushort*)(ws + WS_V);                  // bf16 Wk
  ushort* wvb  = wkb + 65536;                           // bf16 Wv
  ushort* wob  = wkb + 131072;                          // bf16 Wo
  ushort* tmpb = (ushort*)(ws + WS_TMP);                // bf16 attn out [8][2048][256]

  hipMemsetAsync(d_ws, 0, WS_QCOND * sizeof(float), stream);

  k_pool<<<256, 256, 0, stream>>>(q, mask, ws + WS_QPOOL, ws + WS_MSUM);
  k_qcond<<<8, 256, 0, stream>>>(ws + WS_QPOOL, ws + WS_MSUM, Wq, bq, ws + WS_QCOND);
  k_cvt_w<<<96, 256, 0, stream>>>(Wk, Wv, Wo, wkb);
  k_mod<<<128, 256, 0, stream>>>(x, ws + WS_QCOND, Wmod, ws + WS_QT);
  k_off<<<8192, 256, 0, stream>>>(ws + WS_QT, dw_w, dw_b, ln_w, ln_b, offw,
                                  ws + WS_POS, out_pos, out_ref);
  k_cvt_q<<<2048, 256, 0, stream>>>(q, qbuf);           // overwrites QT (dead after k_off)
  k_sample<<<8192, 256, 0, stream>>>(x, ws + WS_POS, xst);
  k_kv_mfma<<<2048, 256, 0, stream>>>(xst, wkb, wvb, bk, bv, kbuf, vbuf);
  k_attn_mfma<<<2048, 256, 0, stream>>>(qbuf, kbuf, vbuf, tmpb);
  k_yproj_mfma<<<4096, 256, 0, stream>>>(tmpb, wob, bo, out_y);
}

// Round 5
// 213.310 us; speedup vs baseline: 4.0710x; 1.3761x over previous
//
#include <hip/hip_runtime.h>
#include <math.h>

typedef unsigned int uint;
typedef unsigned short ushort;
typedef __attribute__((ext_vector_type(8))) short short8;
typedef __attribute__((ext_vector_type(4))) float f32x4;

// Problem constants
constexpr int CB  = 8;      // batch B
constexpr int CL  = 2048;   // sequence length L
constexpr int CC  = 256;    // channels NC
constexpr int CHC = 32;     // head channels
constexpr int CGC = 32;     // group channels
constexpr int CHW = 1024;   // H*W (32*32)
constexpr int CNS = 1024;   // n_sample
constexpr int CBG = 64;     // B * n_groups

// Workspace layout (float offsets)
constexpr size_t WS_QPOOL = 0;          // 2048
constexpr size_t WS_MSUM  = 2048;       // 8
constexpr size_t WS_QCOND = 2176;       // 2048 -> end 4224
constexpr size_t WS_WMOD  = 4224;       // bf16 [8][256][256]  = 262144 f -> 266368
constexpr size_t WS_XT    = 266368;     // bf16 [2][1024][256] = 262144 f -> 528512
constexpr size_t WS_QT    = 528512;     // f32 [8][256][1024] = 2097152 f -> 2625664 (reused as qb bf16 after k_off)
constexpr size_t WS_POS   = 2625664;    // 131072 -> 2756736
constexpr size_t WS_XST   = 2756736;    // bf16 [8][1024][256] = 1048576 f -> 3805312
constexpr size_t WS_KB    = 3805312;    // bf16 [64][1024][32] = 1048576 f -> 4853888
constexpr size_t WS_VB    = 4853888;    // bf16 [64][32][1024] = 1048576 f -> 5902464
constexpr size_t WS_WB    = 5902464;    // bf16 Wk,Wv,Wo       =   98304 f -> 6000768
constexpr size_t WS_TMPB  = 6000768;    // bf16 [8][2048][256] = 2097152 f -> 8097920

static __device__ __forceinline__ ushort f2bf(float f) {
  uint u = __float_as_uint(f);
  return (ushort)((u + 0x7FFFu + ((u >> 16) & 1u)) >> 16);
}
static __device__ __forceinline__ uint pack2bf(float a, float b) {
  return (uint)f2bf(a) | ((uint)f2bf(b) << 16);
}
// truncating bf16 pack of two floats in one v_perm_b32
static __device__ __forceinline__ uint packtrunc(float lo, float hi) {
  return __builtin_amdgcn_perm(__float_as_uint(hi), __float_as_uint(lo), 0x07060302u);
}

// ---------------- K1: masked mean pool (partial sums via atomics) -------------
__global__ void k_pool(const float* __restrict__ q, const float* __restrict__ mask,
                       float* __restrict__ qpool, float* __restrict__ msum) {
  int b  = blockIdx.x >> 5;
  int lc = blockIdx.x & 31;
  int l0 = lc * 64;
  int tid = threadIdx.x;
  __shared__ float mloc[64];
  if (tid < 64) mloc[tid] = mask[b * CL + l0 + tid];
  __syncthreads();
  if (tid == 0) {
    float s = 0.f;
    for (int j = 0; j < 64; j++) s += mloc[j];
    atomicAdd(&msum[b], s);
  }
  float acc = 0.f;
  const float* qb = q + (size_t)(b * CL + l0) * CC + tid;
  for (int j = 0; j < 64; j++) acc += qb[(size_t)j * CC] * mloc[j];
  atomicAdd(&qpool[b * CC + tid], acc);
}

// ---------------- K2: q_cond = pooled_mean @ Wq.T + bq ----------------------
__global__ void k_qcond(const float* __restrict__ qpool, const float* __restrict__ msum,
                        const float* __restrict__ Wq, const float* __restrict__ bq,
                        float* __restrict__ qcond) {
  int b = blockIdx.x, o = threadIdx.x;
  __shared__ float qm[CC];
  float inv = 1.f / (msum[b] + 1e-6f);
  qm[o] = qpool[b * CC + o] * inv;
  __syncthreads();
  float acc = bq[o];
  const float* wrow = Wq + (size_t)o * CC;
  for (int i = 0; i < CC; i++) acc += wrow[i] * qm[i];
  qcond[b * CC + o] = acc;
}

// ---------------- K2c: modulated + demodulated weights -> bf16 --------------
// wmodb[b][o][i] = Wmod[o][i]*(qc[b][i]+1) * rsqrt(sum_i(w^2)+1e-8)
__global__ void k_wprep(const float* __restrict__ Wmod, const float* __restrict__ qcond,
                        ushort* __restrict__ wmodb) {
  int b  = blockIdx.x >> 4;
  int og = blockIdx.x & 15;
  int tid = threadIdx.x;
  int ol = tid >> 4, seg = tid & 15;
  int o = og * 16 + ol;
  const float* wr = Wmod + (size_t)o * CC + seg * 16;
  const float* qc = qcond + b * CC + seg * 16;
  float m[16];
  float ss = 0.f;
  #pragma unroll
  for (int j = 0; j < 16; j++) {
    float v = wr[j] * (qc[j] + 1.f);
    m[j] = v;
    ss += v * v;
  }
  #pragma unroll
  for (int k = 1; k < 16; k <<= 1) ss += __shfl_xor(ss, k, 16);
  float d = rsqrtf(ss + 1e-8f);
  uint u[8];
  #pragma unroll
  for (int j = 0; j < 8; j++) u[j] = pack2bf(m[2 * j] * d, m[2 * j + 1] * d);
  ushort* dst = wmodb + ((size_t)(b * CC + o)) * CC + seg * 16;
  *(uint4*)(dst)     = make_uint4(u[0], u[1], u[2], u[3]);
  *(uint4*)(dst + 8) = make_uint4(u[4], u[5], u[6], u[7]);
}

// ---------------- K2d: x -> x^T bf16 [ref][hw][c] ---------------------------
__global__ void k_xt(const float* __restrict__ x, ushort* __restrict__ xt) {
  int bid = blockIdx.x;               // 2 ref x 4 cblk x 16 hwblk = 128
  int ref  = bid >> 6;
  int cblk = (bid >> 4) & 3;
  int hwblk = bid & 15;
  int tid = threadIdx.x;
  __shared__ float t[64][65];
  int c0 = cblk * 64, hw0 = hwblk * 64;
  const float* src = x + (size_t)ref * CC * CHW;
  int hl = tid & 63, cq = tid >> 6;
  #pragma unroll
  for (int r = 0; r < 16; r++) {
    int cl = cq * 16 + r;
    t[cl][hl] = src[(size_t)(c0 + cl) * CHW + hw0 + hl];
  }
  __syncthreads();
  int cl2 = tid & 63, hq = tid >> 6;
  #pragma unroll
  for (int r = 0; r < 16; r++) {
    int hwl = hq * 16 + r;
    xt[((size_t)(ref * CHW + hw0 + hwl)) * CC + c0 + cl2] = f2bf(t[cl2][hwl]);
  }
}

// ---------------- K3: modulated 1x1 conv via MFMA ---------------------------
__launch_bounds__(256)
__global__ void k_mod_mfma(const ushort* __restrict__ wmodb, const ushort* __restrict__ xt,
                           float* __restrict__ qt) {
  int tid = threadIdx.x;
  int wid = tid >> 6, lane = tid & 63;
  int widx = blockIdx.x * 4 + wid;     // 8192 waves
  int b   = widx >> 10;
  int ot  = (widx >> 6) & 15;
  int hwt = widx & 63;
  int col = lane & 15, g = lane >> 4;
  int O0 = ot * 16, HW0 = hwt * 16;
  const ushort* ap = wmodb + ((size_t)(b * CC + O0 + col)) * CC + g * 8;
  const ushort* bp = xt + ((size_t)((b & 1) * CHW + HW0 + col)) * CC + g * 8;
  f32x4 acc = {0.f, 0.f, 0.f, 0.f};
  #pragma unroll
  for (int ks = 0; ks < 8; ks++) {
    short8 af = *(const short8*)(ap + ks * 32);
    short8 bf = *(const short8*)(bp + ks * 32);
    acc = __builtin_amdgcn_mfma_f32_16x16x32_bf16(af, bf, acc, 0, 0, 0);
  }
  float* dst = qt + ((size_t)(b * CC + O0 + g * 4)) * CHW + HW0 + col;
  #pragma unroll
  for (int r = 0; r < 4; r++) dst[(size_t)r * CHW] = acc[r];
}

// ------- K4: dwconv3x3 + LN + GELU + offset proj + tanh + ref -> pos --------
__global__ void k_off(const float* __restrict__ qt, const float* __restrict__ dww,
                      const float* __restrict__ dwb, const float* __restrict__ lnw,
                      const float* __restrict__ lnb, const float* __restrict__ offw,
                      float* __restrict__ posw, float* __restrict__ out_pos,
                      float* __restrict__ out_ref) {
  int bg   = blockIdx.x >> 7;
  int pblk = blockIdx.x & 127;
  int tid  = threadIdx.x;
  int c = tid & 31, pp = tid >> 5;
  int p0 = pblk * 8;
  int yy = p0 >> 5;
  int xx = (p0 & 31) + pp;
  int p  = p0 + pp;
  const float* src = qt + ((size_t)bg * CGC + c) * CHW;
  float acc = dwb[c];
  #pragma unroll
  for (int ky = 0; ky < 3; ky++) {
    int yr = yy + ky - 1;
    if (yr < 0 || yr > 31) continue;
    #pragma unroll
    for (int kx = 0; kx < 3; kx++) {
      int xc = xx + kx - 1;
      if (xc < 0 || xc > 31) continue;
      acc += dww[c * 9 + ky * 3 + kx] * src[yr * 32 + xc];
    }
  }
  float s1 = acc, s2 = acc * acc;
  #pragma unroll
  for (int m = 1; m < 32; m <<= 1) { s1 += __shfl_xor(s1, m, 32); s2 += __shfl_xor(s2, m, 32); }
  float mu  = s1 * (1.f / 32.f);
  float var = s2 * (1.f / 32.f) - mu * mu;
  float tn  = (acc - mu) * rsqrtf(var + 1e-5f) * lnw[c] + lnb[c];
  float g   = 0.5f * tn * (1.f + erff(tn * 0.70710678118654752f));
  float sy = offw[c] * g, sx = offw[32 + c] * g;
  #pragma unroll
  for (int m = 1; m < 32; m <<= 1) { sy += __shfl_xor(sy, m, 32); sx += __shfl_xor(sx, m, 32); }
  if (c < 2) {
    float v   = (c == 0) ? sy : sx;
    float off = tanhf(v) * (2.f / 31.f);
    float coord = (c == 0) ? (float)yy : (float)xx;
    float ref = (0.5f + coord) * (2.f / 31.f) - 1.f;
    float pv  = off + ref;
    int oidx = bg * 2048 + p * 2 + c;
    posw[oidx]    = pv;
    out_pos[oidx] = pv;
    out_ref[oidx] = ref;
  }
}

// ---------------- K5: bilinear grid sample -> xs^T bf16 [b][n][i] -----------
__global__ void k_sample(const float* __restrict__ x, const float* __restrict__ posw,
                         ushort* __restrict__ xst) {
  int bg   = blockIdx.x >> 7;
  int pblk = blockIdx.x & 127;
  int tid  = threadIdx.x;
  int c = tid & 31, pp = tid >> 5;
  int p = pblk * 8 + pp;
  float py = posw[bg * 2048 + p * 2 + 0];
  float px = posw[bg * 2048 + p * 2 + 1];
  float gx = (px + 1.f) * 15.5f;
  float gy = (py + 1.f) * 15.5f;
  float x0f = floorf(gx), y0f = floorf(gy);
  float wx = gx - x0f, wy = gy - y0f;
  int ix0 = (int)x0f, iy0 = (int)y0f;
  const float* img = x + (size_t)((bg >> 3) & 1) * CC * CHW + ((size_t)((bg & 7) * CGC + c)) * CHW;
  float acc = 0.f;
  #pragma unroll
  for (int dy = 0; dy < 2; dy++) {
    int iy = iy0 + dy;
    if (iy < 0 || iy > 31) continue;
    float wyv = dy ? wy : 1.f - wy;
    #pragma unroll
    for (int dx = 0; dx < 2; dx++) {
      int ix = ix0 + dx;
      if (ix < 0 || ix > 31) continue;
      float wxv = dx ? wx : 1.f - wx;
      acc += wyv * wxv * img[iy * 32 + ix];
    }
  }
  xst[((size_t)((bg >> 3) * CNS) + p) * CC + (bg & 7) * CGC + c] = f2bf(acc);
}

// ---------------- K5b: convert Wk/Wv/Wo -> bf16 (row-major preserved) -------
__global__ void k_cvt_w(const float* __restrict__ Wk, const float* __restrict__ Wv,
                        const float* __restrict__ Wo, ushort* __restrict__ wb) {
  int t = blockIdx.x * 256 + threadIdx.x;
  int which = t >> 13;
  size_t off = ((size_t)(t & 8191)) * 8;
  const float* src = (which == 0) ? Wk : (which == 1) ? Wv : Wo;
  float4 a = *(const float4*)(src + off);
  float4 b = *(const float4*)(src + off + 4);
  uint4 r;
  r.x = pack2bf(a.x, a.y); r.y = pack2bf(a.z, a.w);
  r.z = pack2bf(b.x, b.y); r.w = pack2bf(b.z, b.w);
  *(uint4*)(wb + (size_t)which * 65536 + off) = r;
}

// ---------------- K6: fused K/V projection via MFMA -------------------------
__launch_bounds__(256)
__global__ void k_kv_mfma(const ushort* __restrict__ xst, const ushort* __restrict__ wkb,
                          const ushort* __restrict__ wvb, const float* __restrict__ bk,
                          const float* __restrict__ bv, ushort* __restrict__ kb,
                          ushort* __restrict__ vb) {
  int tid = threadIdx.x;
  int wid = tid >> 6, lane = tid & 63;
  int widx = blockIdx.x * 4 + wid;       // 8192 waves
  int b  = widx >> 10;
  int nt = (widx >> 4) & 63;
  int ot = widx & 15;
  int col = lane & 15, g = lane >> 4;
  int N0 = nt * 16, O0 = ot * 16;

  const ushort* xsb = xst + ((size_t)(b * CNS + N0 + col)) * CC + g * 8;
  const ushort* wkp = wkb + (size_t)(O0 + col) * CC + g * 8;
  const ushort* wvp = wvb + (size_t)(O0 + col) * CC + g * 8;

  f32x4 ka, va;
  #pragma unroll
  for (int r = 0; r < 4; r++) ka[r] = bk[O0 + g * 4 + r];
  float bvv = bv[O0 + col];
  #pragma unroll
  for (int r = 0; r < 4; r++) va[r] = bvv;

  #pragma unroll
  for (int ks = 0; ks < 8; ks++) {
    short8 xf = *(const short8*)(xsb + ks * 32);
    short8 kf = *(const short8*)(wkp + ks * 32);
    short8 vf = *(const short8*)(wvp + ks * 32);
    ka = __builtin_amdgcn_mfma_f32_16x16x32_bf16(kf, xf, ka, 0, 0, 0);
    va = __builtin_amdgcn_mfma_f32_16x16x32_bf16(xf, vf, va, 0, 0, 0);
  }

  {
    int hh = O0 >> 5;
    int c0 = (O0 & 31) + g * 4;
    uint2 w;
    w.x = pack2bf(ka[0], ka[1]);
    w.y = pack2bf(ka[2], ka[3]);
    *(uint2*)(kb + ((size_t)((b * 8 + hh) * CNS + N0 + col)) * CHC + c0) = w;
  }
  {
    int o = O0 + col;
    int hh = o >> 5;
    uint2 w;
    w.x = pack2bf(va[0], va[1]);
    w.y = pack2bf(va[2], va[3]);
    *(uint2*)(vb + ((size_t)((b * 8 + hh) * CHC + (o & 31))) * CNS + N0 + g * 4) = w;
  }
}

// ---------------- K6b: convert q -> bf16, pre-scaled by scale*log2(e) -------
__global__ void k_cvt_q(const float* __restrict__ q, ushort* __restrict__ qb) {
  const float scale = 0.17677669529663687f * 1.4426950408889634f;
  size_t i0 = ((size_t)blockIdx.x * 256 + threadIdx.x) * 8;
  float4 a = *(const float4*)(q + i0);
  float4 b = *(const float4*)(q + i0 + 4);
  uint4 r;
  r.x = pack2bf(a.x * scale, a.y * scale);
  r.y = pack2bf(a.z * scale, a.w * scale);
  r.z = pack2bf(b.x * scale, b.y * scale);
  r.w = pack2bf(b.z * scale, b.w * scale);
  *(uint4*)(qb + i0) = r;
}

// ---------------- K7: MFMA flash attention, 2 m-tiles per wave ---------------
__launch_bounds__(256, 4)
__global__ void k_attn_mfma(const ushort* __restrict__ qb, const ushort* __restrict__ kb,
                            const ushort* __restrict__ vb, ushort* __restrict__ tmpb) {
  int bh = blockIdx.x >> 4;          // 64
  int mb = blockIdx.x & 15;          // 16 m-blocks of 128 rows
  int b = bh >> 3, h = bh & 7;
  int tid = threadIdx.x;
  int wid = tid >> 6, lane = tid & 63;
  int col = lane & 15, g = lane >> 4;
  int mA = mb * 128 + wid * 32 + col;

  __shared__ ushort plds_all[4][2][1024];
  char* pwA = (char*)&plds_all[wid][0][0];
  char* pwB = (char*)&plds_all[wid][1][0];
  int swz = (col & 7) << 4;
  int wb0 = col * 128 + g * 8;       // disjoint bitfields: +f*32 ^ swz ok
  int rb0 = (col * 128 + g * 16) ^ swz;
  int rb1 = (col * 128 + 64 + g * 16) ^ swz;

  const ushort* qpA = qb + ((size_t)(b * CL + mA)) * CC + h * CHC + g * 8;
  short8 qfA = *(const short8*)qpA;
  short8 qfB = *(const short8*)(qpA + 16 * CC);

  const ushort* kbase = kb + (size_t)bh * 32768;   // [n][c]
  const ushort* vbase = vb + (size_t)bh * 32768;   // [c][n]

  f32x4 oA0 = {0.f,0.f,0.f,0.f}, oA1 = {0.f,0.f,0.f,0.f};
  f32x4 oB0 = {0.f,0.f,0.f,0.f}, oB1 = {0.f,0.f,0.f,0.f};
  float lA = 0.f, lB = 0.f;

  for (int ch = 0; ch < 16; ch++) {
    short8 kf0 = *(const short8*)(kbase + (size_t)(ch * 64 +  0 + col) * 32 + g * 8);
    short8 kf1 = *(const short8*)(kbase + (size_t)(ch * 64 + 16 + col) * 32 + g * 8);
    short8 kf2 = *(const short8*)(kbase + (size_t)(ch * 64 + 32 + col) * 32 + g * 8);
    short8 kf3 = *(const short8*)(kbase + (size_t)(ch * 64 + 48 + col) * 32 + g * 8);
    short8 vf00 = *(const short8*)(vbase + (size_t)(col     ) * 1024 + ch * 64 +  0 + g * 8);
    short8 vf01 = *(const short8*)(vbase + (size_t)(col     ) * 1024 + ch * 64 + 32 + g * 8);
    short8 vf10 = *(const short8*)(vbase + (size_t)(col + 16) * 1024 + ch * 64 +  0 + g * 8);
    short8 vf11 = *(const short8*)(vbase + (size_t)(col + 16) * 1024 + ch * 64 + 32 + g * 8);

    f32x4 zero = {0.f,0.f,0.f,0.f};
    f32x4 sA0 = __builtin_amdgcn_mfma_f32_16x16x32_bf16(kf0, qfA, zero, 0, 0, 0);
    f32x4 sA1 = __builtin_amdgcn_mfma_f32_16x16x32_bf16(kf1, qfA, zero, 0, 0, 0);
    f32x4 sA2 = __builtin_amdgcn_mfma_f32_16x16x32_bf16(kf2, qfA, zero, 0, 0, 0);
    f32x4 sA3 = __builtin_amdgcn_mfma_f32_16x16x32_bf16(kf3, qfA, zero, 0, 0, 0);
    f32x4 sB0 = __builtin_amdgcn_mfma_f32_16x16x32_bf16(kf0, qfB, zero, 0, 0, 0);
    f32x4 sB1 = __builtin_amdgcn_mfma_f32_16x16x32_bf16(kf1, qfB, zero, 0, 0, 0);
    f32x4 sB2 = __builtin_amdgcn_mfma_f32_16x16x32_bf16(kf2, qfB, zero, 0, 0, 0);
    f32x4 sB3 = __builtin_amdgcn_mfma_f32_16x16x32_bf16(kf3, qfB, zero, 0, 0, 0);

    // ---- tile A: exp2 (q pre-scaled by log2e), sum, trunc-pack, stage ----
    {
      float p0, p1, p2, p3;
      float ps = 0.f;
      #pragma unroll
      for (int f = 0; f < 4; f++) {
        f32x4 s = (f == 0) ? sA0 : (f == 1) ? sA1 : (f == 2) ? sA2 : sA3;
        p0 = exp2f(s[0]); p1 = exp2f(s[1]); p2 = exp2f(s[2]); p3 = exp2f(s[3]);
        ps += (p0 + p1) + (p2 + p3);
        uint lo = packtrunc(p0, p1);
        uint hi = packtrunc(p2, p3);
        *(uint2*)(pwA + ((wb0 + f * 32) ^ swz)) = make_uint2(lo, hi);
      }
      lA += ps;
    }
    {
      float p0, p1, p2, p3;
      float ps = 0.f;
      #pragma unroll
      for (int f = 0; f < 4; f++) {
        f32x4 s = (f == 0) ? sB0 : (f == 1) ? sB1 : (f == 2) ? sB2 : sB3;
        p0 = exp2f(s[0]); p1 = exp2f(s[1]); p2 = exp2f(s[2]); p3 = exp2f(s[3]);
        ps += (p0 + p1) + (p2 + p3);
        uint lo = packtrunc(p0, p1);
        uint hi = packtrunc(p2, p3);
        *(uint2*)(pwB + ((wb0 + f * 32) ^ swz)) = make_uint2(lo, hi);
      }
      lB += ps;
    }

    short8 pfA0 = *(const short8*)(pwA + rb0);
    short8 pfA1 = *(const short8*)(pwA + rb1);
    short8 pfB0 = *(const short8*)(pwB + rb0);
    short8 pfB1 = *(const short8*)(pwB + rb1);

    oA0 = __builtin_amdgcn_mfma_f32_16x16x32_bf16(vf00, pfA0, oA0, 0, 0, 0);
    oA0 = __builtin_amdgcn_mfma_f32_16x16x32_bf16(vf01, pfA1, oA0, 0, 0, 0);
    oA1 = __builtin_amdgcn_mfma_f32_16x16x32_bf16(vf10, pfA0, oA1, 0, 0, 0);
    oA1 = __builtin_amdgcn_mfma_f32_16x16x32_bf16(vf11, pfA1, oA1, 0, 0, 0);
    oB0 = __builtin_amdgcn_mfma_f32_16x16x32_bf16(vf00, pfB0, oB0, 0, 0, 0);
    oB0 = __builtin_amdgcn_mfma_f32_16x16x32_bf16(vf01, pfB1, oB0, 0, 0, 0);
    oB1 = __builtin_amdgcn_mfma_f32_16x16x32_bf16(vf10, pfB0, oB1, 0, 0, 0);
    oB1 = __builtin_amdgcn_mfma_f32_16x16x32_bf16(vf11, pfB1, oB1, 0, 0, 0);
  }

  lA += __shfl_xor(lA, 16); lA += __shfl_xor(lA, 32);
  lB += __shfl_xor(lB, 16); lB += __shfl_xor(lB, 32);
  float rlA = 1.f / lA, rlB = 1.f / lB;

  ushort* opA = tmpb + ((size_t)(b * CL + mA)) * CC + h * CHC;
  ushort* opB = opA + 16 * CC;
  {
    uint2 w0, w1;
    w0.x = pack2bf(oA0[0] * rlA, oA0[1] * rlA);
    w0.y = pack2bf(oA0[2] * rlA, oA0[3] * rlA);
    w1.x = pack2bf(oA1[0] * rlA, oA1[1] * rlA);
    w1.y = pack2bf(oA1[2] * rlA, oA1[3] * rlA);
    *(uint2*)(opA + g * 4) = w0;
    *(uint2*)(opA + 16 + g * 4) = w1;
  }
  {
    uint2 w0, w1;
    w0.x = pack2bf(oB0[0] * rlB, oB0[1] * rlB);
    w0.y = pack2bf(oB0[2] * rlB, oB0[3] * rlB);
    w1.x = pack2bf(oB1[0] * rlB, oB1[1] * rlB);
    w1.y = pack2bf(oB1[2] * rlB, oB1[3] * rlB);
    *(uint2*)(opB + g * 4) = w0;
    *(uint2*)(opB + 16 + g * 4) = w1;
  }
}

// ---------------- K8: y = tmp_bf @ Wo_bf^T + bo via MFMA (4 o-tiles/wave) ---
__launch_bounds__(256)
__global__ void k_yproj_mfma(const ushort* __restrict__ tmpb, const ushort* __restrict__ wob,
                             const float* __restrict__ bo, float* __restrict__ y) {
  int tid = threadIdx.x;
  int wid = tid >> 6, lane = tid & 63;
  int widx = blockIdx.x * 4 + wid;      // 4096 waves
  int rt = widx >> 2;                   // 1024 row tiles
  int og = widx & 3;                    // 4 o-groups of 64
  int col = lane & 15, g = lane >> 4;
  int R0 = rt * 16, O0 = og * 64;

  const ushort* ap = tmpb + ((size_t)(R0 + col)) * CC + g * 8;
  const ushort* bp = wob + (size_t)(O0 + col) * CC + g * 8;

  f32x4 acc[4];
  #pragma unroll
  for (int o4 = 0; o4 < 4; o4++) {
    float bb = bo[O0 + o4 * 16 + col];
    #pragma unroll
    for (int r = 0; r < 4; r++) acc[o4][r] = bb;
  }

  #pragma unroll
  for (int ks = 0; ks < 8; ks++) {
    short8 af = *(const short8*)(ap + ks * 32);
    #pragma unroll
    for (int o4 = 0; o4 < 4; o4++) {
      short8 bf = *(const short8*)(bp + (size_t)o4 * 16 * CC + ks * 32);
      acc[o4] = __builtin_amdgcn_mfma_f32_16x16x32_bf16(af, bf, acc[o4], 0, 0, 0);
    }
  }

  #pragma unroll
  for (int o4 = 0; o4 < 4; o4++)
    #pragma unroll
    for (int r = 0; r < 4; r++)
      y[(size_t)(R0 + g * 4 + r) * CC + O0 + o4 * 16 + col] = acc[o4][r];
}

extern "C" void kernel_launch(void* const* d_in, const int* in_sizes, int n_in,
                              void* d_out, int out_size, void* d_ws, size_t ws_size,
                              hipStream_t stream) {
  const float* x    = (const float*)d_in[0];
  const float* q    = (const float*)d_in[1];
  const float* mask = (const float*)d_in[2];
  const float* Wq   = (const float*)d_in[3];
  const float* bq   = (const float*)d_in[4];
  const float* Wmod = (const float*)d_in[5];
  const float* dw_w = (const float*)d_in[6];
  const float* dw_b = (const float*)d_in[7];
  const float* ln_w = (const float*)d_in[8];
  const float* ln_b = (const float*)d_in[9];
  const float* offw = (const float*)d_in[10];
  const float* Wk   = (const float*)d_in[11];
  const float* bk   = (const float*)d_in[12];
  const float* Wv   = (const float*)d_in[13];
  const float* bv   = (const float*)d_in[14];
  const float* Wo   = (const float*)d_in[15];
  const float* bo   = (const float*)d_in[16];

  float* ws = (float*)d_ws;
  float* out = (float*)d_out;
  float* out_y   = out;
  float* out_pos = out + (size_t)CB * CL * CC;
  float* out_ref = out_pos + (size_t)CBG * CHW * 2;

  ushort* wmodb = (ushort*)(ws + WS_WMOD);
  ushort* xt    = (ushort*)(ws + WS_XT);
  float*  qt    = ws + WS_QT;
  ushort* qbuf  = (ushort*)(ws + WS_QT);      // overlays qt AFTER k_off
  ushort* xst   = (ushort*)(ws + WS_XST);
  ushort* kbuf  = (ushort*)(ws + WS_KB);
  ushort* vbuf  = (ushort*)(ws + WS_VB);
  ushort* wkb   = (ushort*)(ws + WS_WB);
  ushort* wvb   = wkb + 65536;
  ushort* wob   = wkb + 131072;
  ushort* tmpb  = (ushort*)(ws + WS_TMPB);

  hipMemsetAsync(d_ws, 0, WS_QCOND * sizeof(float), stream);

  k_pool<<<256, 256, 0, stream>>>(q, mask, ws + WS_QPOOL, ws + WS_MSUM);
  k_qcond<<<8, 256, 0, stream>>>(ws + WS_QPOOL, ws + WS_MSUM, Wq, bq, ws + WS_QCOND);
  k_cvt_w<<<96, 256, 0, stream>>>(Wk, Wv, Wo, wkb);
  k_xt<<<128, 256, 0, stream>>>(x, xt);
  k_wprep<<<128, 256, 0, stream>>>(Wmod, ws + WS_QCOND, wmodb);
  k_mod_mfma<<<2048, 256, 0, stream>>>(wmodb, xt, qt);
  k_off<<<8192, 256, 0, stream>>>(qt, dw_w, dw_b, ln_w, ln_b, offw,
                                  ws + WS_POS, out_pos, out_ref);
  k_cvt_q<<<2048, 256, 0, stream>>>(q, qbuf);           // overwrites qt (dead after k_off)
  k_sample<<<8192, 256, 0, stream>>>(x, ws + WS_POS, xst);
  k_kv_mfma<<<2048, 256, 0, stream>>>(xst, wkb, wvb, bk, bv, kbuf, vbuf);
  k_attn_mfma<<<1024, 256, 0, stream>>>(qbuf, kbuf, vbuf, tmpb);
  k_yproj_mfma<<<1024, 256, 0, stream>>>(tmpb, wob, bo, out_y);
}